// Round 6
// baseline (222.525 us; speedup 1.0000x reference)
//
#include <hip/hip_runtime.h>
#include <math.h>

#define BB 128
#define TT 1024
#define II 128
#define HH 512
#define GG 2048           // 4*H
#define BT (BB*TT)
#define LMAX 10
#define NBUCK 13          // 0:out0, 1:outH, 2..11: spine lvl 0..9; [13]=spin barrier

#define BM 128            // rows per tile (k_gemm)
#define SM 64             // rows per tile (k_spineH)

typedef unsigned short u16;
typedef __attribute__((ext_vector_type(4))) u16 u16x4;
typedef __attribute__((ext_vector_type(8))) u16 u16x8;
typedef __attribute__((ext_vector_type(8))) short bf16x8;
typedef __attribute__((ext_vector_type(4))) float f32x4;

__device__ __forceinline__ float sigf(float v) { return 1.0f / (1.0f + __expf(-v)); }

__device__ __forceinline__ u16 f2b(float f) {
    unsigned int x = __float_as_uint(f);
    return (u16)((x + 0x7fffu + ((x >> 16) & 1u)) >> 16);   // RNE, finite inputs
}

// bucket list geometry
__host__ __device__ __forceinline__ void buck_geom(int bkt, int CAP0, int* off, int* cap) {
    if (bkt == 0) { *off = 0; *cap = CAP0; return; }
    int o = CAP0;
    if (bkt == 1) { *off = o; *cap = 2048; return; } o += 2048;  // outH
    if (bkt == 2) { *off = o; *cap = 2048; return; } o += 2048;  // spine0
    if (bkt == 3) { *off = o; *cap = 512;  return; } o += 512;   // spine1
    if (bkt == 4) { *off = o; *cap = 128;  return; } o += 128;   // spine2
    *off = o + (bkt - 5) * 64; *cap = 64;                         // spine3..9
}
#define LIST_EXTRA (2048 + 2048 + 512 + 128 + 7*64)

__device__ __forceinline__ int block_scan_excl(int* scan, int tid, int v, int* total) {
    scan[tid] = v;
    __syncthreads();
    for (int s = 1; s < 256; s <<= 1) {
        int a = scan[tid];
        int u = (tid >= s) ? scan[tid - s] : 0;
        __syncthreads();
        scan[tid] = a + u;
        __syncthreads();
    }
    int incl = scan[tid];
    *total = scan[255];
    __syncthreads();
    return incl - v;
}

// ---------------------------------------------------------------- k_wcvt
__global__ void k_wcvt(const float* __restrict__ Wih, const float* __restrict__ Whh,
                       u16* __restrict__ wihb, u16* __restrict__ whhb,
                       int* __restrict__ levelCount) {
    if (blockIdx.x == 0 && threadIdx.x <= NBUCK) levelCount[threadIdx.x] = 0;
    int i = blockIdx.x * 256 + threadIdx.x;
    const int NW = GG * II / 4;
    const int NH = GG * HH / 4;
    if (i < NW) {
        float4 v = ((const float4*)Wih)[i];
        u16x4 u = { f2b(v.x), f2b(v.y), f2b(v.z), f2b(v.w) };
        ((u16x4*)wihb)[i] = u;
    } else if (i < NW + NH) {
        int j = i - NW;
        float4 v = ((const float4*)Whh)[j];
        u16x4 u = { f2b(v.x), f2b(v.y), f2b(v.z), f2b(v.w) };
        ((u16x4*)whhb)[j] = u;
    }
}

// ---------------------------------------------------------------- k_prep
// one block per batch row: mask, word count, gather selection, needed marks,
// chain levels, bucket lists (spine/leaf), slots, x->bf16, pad-row zeroing.
__global__ __launch_bounds__(256) void k_prep(
    const int* __restrict__ mask, const int* __restrict__ length,
    const float* __restrict__ x, float* __restrict__ wnOut,
    int* __restrict__ levelCount, int2* __restrict__ levelList,
    int* __restrict__ slotOf, u16* __restrict__ xb, float* __restrict__ out,
    int K, int R, int CAP0) {
    __shared__ unsigned char sm[TT];
    __shared__ unsigned char sne[TT];
    __shared__ u16 sgp[TT];
    __shared__ int scan[256];
    __shared__ int cnt[NBUCK], cnt2[NBUCK], bas[NBUCK];
    __shared__ u16 spos[256];
    __shared__ u16 zlist[256];
    __shared__ int zn;

    int b = blockIdx.x, tid = threadIdx.x;
    int len = length[b];
    int t0 = tid * 4;
    if (tid == 0) zn = 0;

    int4 mk = ((const int4*)(mask + (size_t)b * TT))[tid];
    int mraw[4] = { mk.x, mk.y, mk.z, mk.w };
    unsigned char mv[4];
    int lzero = 0;
#pragma unroll
    for (int j = 0; j < 4; ++j) {
        int t = t0 + j;
        unsigned char m = (t == len - 1) ? 1 : ((t == 0) ? 0 : (mraw[j] != 0));
        mv[j] = m;
        sm[t] = m;
        sgp[t] = 0;
        lzero += !m;
    }

    int Z;
    int zbase = block_scan_excl(scan, tid, lzero, &Z);
    int wn = TT - Z;
    if (tid == 0) wnOut[b] = (float)wn;
    int need = K - wn;

    int psel[4];
    int lpad = 0;
    {
        int zb = zbase;
#pragma unroll
        for (int j = 0; j < 4; ++j) {
            int sel = mv[j] | ((Z - zb) <= need ? 1 : 0);
            psel[j] = sel;
            lpad += sel;
            zb += !mv[j];
        }
    }
    int ptot;
    int pbase = block_scan_excl(scan, tid, lpad, &ptot);
    {
        int k = pbase;
#pragma unroll
        for (int j = 0; j < 4; ++j) {
            int t = t0 + j;
            if (psel[j]) {
                sgp[t - 1] = (u16)(k + 1);          // t==0 never selected (K << T)
                if (t - 1 >= len) {                 // inactive source -> zero out row
                    int zi = atomicAdd(&zn, 1);
                    if (zi < 256) zlist[zi] = (u16)k;
                }
                ++k;
            }
        }
    }
    __syncthreads();

    // needed (short forward chain walk) + chain level
    int nev[4], lvlv[4];
    int lne = 0;
#pragma unroll
    for (int j = 0; j < 4; ++j) {
        int t = t0 + j;
        int ne = 0;
        if (t < len) {
            int tt = t;
            ne = sgp[tt] != 0;
            while (!ne && tt + 1 < TT && tt + 1 < len && sm[tt + 1]) { ++tt; ne = sgp[tt] != 0; }
        }
        nev[j] = ne;
        sne[t] = (unsigned char)ne;
        lne += ne;
        int l = 0;
        if (mv[j]) { int tt = t; while (tt >= 0 && sm[tt] && l < LMAX - 1) { ++l; --tt; } }
        lvlv[j] = l;
    }

    int ntot;
    int nbase = block_scan_excl(scan, tid, lne, &ntot);   // syncs inside; sne visible
    {
        int r = nbase;
        int sv[4];
#pragma unroll
        for (int j = 0; j < 4; ++j) {
            if (nev[j]) { sv[j] = b * R + r; if (r < 256) spos[r] = (u16)(t0 + j); }
            else sv[j] = -1;
            r += nev[j];
        }
        *(int4*)(slotOf + (size_t)b * TT + t0) = make_int4(sv[0], sv[1], sv[2], sv[3]);
    }

    if (tid < NBUCK) { cnt[tid] = 0; cnt2[tid] = 0; }
    __syncthreads();
    int bktv[4];
#pragma unroll
    for (int j = 0; j < 4; ++j) {
        bktv[j] = -1;
        if (nev[j]) {
            int t = t0 + j;
            int pred = (t + 1 < TT) && sm[t + 1] && sne[t + 1];
            int bkt = pred ? (2 + lvlv[j]) : (lvlv[j] ? 1 : 0);
            bktv[j] = bkt;
            atomicAdd(&cnt[bkt], 1);
        }
    }
    __syncthreads();
    if (tid < NBUCK) bas[tid] = cnt[tid] ? atomicAdd(&levelCount[tid], cnt[tid]) : 0;
    __syncthreads();
#pragma unroll
    for (int j = 0; j < 4; ++j) if (nev[j]) {
        int t = t0 + j;
        int bkt = bktv[j];
        int r = atomicAdd(&cnt2[bkt], 1);
        int off, cap;
        buck_geom(bkt, CAP0, &off, &cap);
        int idx = bas[bkt] + r;
        unsigned int y = ((bkt >= 2) ? 0x80000000u : 0u) | (unsigned int)sgp[t];
        if (idx < cap) levelList[off + idx] = make_int2(b * TT + t, (int)y);
    }
    __syncthreads();

    // x rows of needed slots -> bf16
    int nv = (ntot < 256 ? ntot : 256) * 16;
    for (int idx = tid; idx < nv; idx += 256) {
        int r = idx >> 4, part = idx & 15;
        int t = spos[r];
        const float* src = x + ((size_t)b * TT + t) * II + part * 8;
        float4 v0 = ((const float4*)src)[0];
        float4 v1 = ((const float4*)src)[1];
        u16x8 u = { f2b(v0.x), f2b(v0.y), f2b(v0.z), f2b(v0.w),
                    f2b(v1.x), f2b(v1.y), f2b(v1.z), f2b(v1.w) };
        *(u16x8*)(xb + ((size_t)b * R + r) * II + part * 8) = u;
    }
    // zero gather rows with inactive sources
    int znv = zn < 256 ? zn : 256;
    for (int idx = tid; idx < znv * 128; idx += 256) {
        int e = idx >> 7, q = idx & 127;
        ((float4*)(out + ((size_t)b * K + zlist[e]) * HH))[q] = make_float4(0.f, 0.f, 0.f, 0.f);
    }
}

// ---------------------------------------------------------------- k_gemm (LDS-free MFMA)
// BM=128 rows x 128 gate cols per block; fragments loaded straight from global.
template<int HASH>
__global__ __launch_bounds__(256) void k_gemm(
    int cntIdx, int listOff, int cap,
    const int* __restrict__ levelCount, const int2* __restrict__ levelList,
    const u16* __restrict__ xb, const u16* __restrict__ wihb, const u16* __restrict__ whhb,
    const float* __restrict__ bih, const float* __restrict__ bhh,
    const int* __restrict__ slotOf, u16* __restrict__ hb, float* __restrict__ cbuf,
    float* __restrict__ out, int K) {
    int n = levelCount[cntIdx];
    if (n > cap) n = cap;
    int nt = (n + BM - 1) / BM;
    if ((int)blockIdx.x >= nt) return;
    int base = blockIdx.x * BM;
    int nrow = min(BM, n - base);
    int jg = blockIdx.y;                      // 0..15 -> h-cols [jg*32, jg*32+32)
    const int2* list = levelList + listOff + base;

    __shared__ int sSlot[BM], sPrev[BM], sAux[BM];
    int tid = threadIdx.x;
    if (tid < BM) {
        int2 e = list[(tid < nrow) ? tid : 0];
        int pos = e.x;
        sSlot[tid] = slotOf[pos];
        sPrev[tid] = HASH ? slotOf[pos - 1] : 0;
        unsigned int y = (unsigned int)e.y;
        int grank = (int)(y & 0xFFFFu);
        sAux[tid] = (int)((y & 0x80000000u) | (unsigned int)(grank ? ((pos >> 10) * K + grank) : 0));
    }
    __syncthreads();

    int w = tid >> 6, l = tid & 63, u = l & 15, kg = l >> 4;
    int r0 = w * 32 + u, r1 = r0 + 16;
    int xs0 = sSlot[r0], xs1 = sSlot[r1];
    int gjv[8];
#pragma unroll
    for (int cb = 0; cb < 8; ++cb) gjv[cb] = (cb >> 1) * HH + jg * 32 + (cb & 1) * 16 + u;

    f32x4 acc[2][8];
#pragma unroll
    for (int rb = 0; rb < 2; ++rb)
#pragma unroll
        for (int cb = 0; cb < 8; ++cb) acc[rb][cb] = (f32x4)0.f;

    // chunk 0: x part (K=128)
    {
        const u16* a0 = xb + (size_t)xs0 * II;
        const u16* a1 = xb + (size_t)xs1 * II;
#pragma unroll
        for (int s = 0; s < 4; ++s) {
            int ko = s * 32 + kg * 8;
            bf16x8 af0 = *(const bf16x8*)(a0 + ko);
            bf16x8 af1 = *(const bf16x8*)(a1 + ko);
#pragma unroll
            for (int cb = 0; cb < 8; ++cb) {
                bf16x8 bf = *(const bf16x8*)(wihb + (size_t)gjv[cb] * II + ko);
                acc[0][cb] = __builtin_amdgcn_mfma_f32_16x16x32_bf16(af0, bf, acc[0][cb], 0, 0, 0);
                acc[1][cb] = __builtin_amdgcn_mfma_f32_16x16x32_bf16(af1, bf, acc[1][cb], 0, 0, 0);
            }
        }
    }
    if (HASH) {
        int hp0 = sPrev[r0], hp1 = sPrev[r1];
        const u16* a0 = hb + (size_t)hp0 * HH;
        const u16* a1 = hb + (size_t)hp1 * HH;
        for (int kc = 0; kc < 4; ++kc) {
#pragma unroll
            for (int s = 0; s < 4; ++s) {
                int ko = kc * 128 + s * 32 + kg * 8;
                bf16x8 af0 = *(const bf16x8*)(a0 + ko);
                bf16x8 af1 = *(const bf16x8*)(a1 + ko);
#pragma unroll
                for (int cb = 0; cb < 8; ++cb) {
                    bf16x8 bf = *(const bf16x8*)(whhb + (size_t)gjv[cb] * HH + ko);
                    acc[0][cb] = __builtin_amdgcn_mfma_f32_16x16x32_bf16(af0, bf, acc[0][cb], 0, 0, 0);
                    acc[1][cb] = __builtin_amdgcn_mfma_f32_16x16x32_bf16(af1, bf, acc[1][cb], 0, 0, 0);
                }
            }
        }
    }

    // epilogue: lane covers h-cols (h0, h0+16) x 4 gates
    int h0 = jg * 32 + u;
    float b_i[2], b_f[2], b_g[2], b_o[2];
#pragma unroll
    for (int h = 0; h < 2; ++h) {
        int hc = h0 + h * 16;
        b_i[h] = bih[hc] + bhh[hc];
        b_f[h] = bih[HH + hc] + bhh[HH + hc];
        b_g[h] = bih[2 * HH + hc] + bhh[2 * HH + hc];
        b_o[h] = bih[3 * HH + hc] + bhh[3 * HH + hc];
    }
#pragma unroll
    for (int rb = 0; rb < 2; ++rb) {
#pragma unroll
        for (int r = 0; r < 4; ++r) {
            int m = w * 32 + rb * 16 + kg * 4 + r;
            if (m < nrow) {
                int aux = sAux[m];
                int oi = aux & 0x7FFFFFFF;
                int sp = HASH ? sPrev[m] : 0;
                int sl = sSlot[m];
#pragma unroll
                for (int h = 0; h < 2; ++h) {
                    int hc = h0 + h * 16;
                    float gi = acc[rb][0 + h][r] + b_i[h];
                    float gf = acc[rb][2 + h][r] + b_f[h];
                    float gg = acc[rb][4 + h][r] + b_g[h];
                    float go = acc[rb][6 + h][r] + b_o[h];
                    float cin = HASH ? cbuf[(size_t)sp * HH + hc] : 0.f;
                    float c2 = sigf(gf) * cin + sigf(gi) * tanhf(gg);
                    float h2 = sigf(go) * tanhf(c2);
                    if (oi) out[(size_t)(oi - 1) * HH + hc] = h2;
                    if (aux < 0) {
                        hb[(size_t)sl * HH + hc] = f2b(h2);
                        cbuf[(size_t)sl * HH + hc] = c2;
                    }
                }
            }
        }
    }
}

// ---------------------------------------------------------------- k_spineH (spine lvl 2..9)
// grid (1, 32): 32 blocks, 64-col slices; SM=64 rows/tile; spin barrier between levels.
__global__ __launch_bounds__(256) void k_spineH(
    int CAP0, const int* __restrict__ levelCount, const int2* __restrict__ levelList,
    const u16* __restrict__ xb, const u16* __restrict__ wihb, const u16* __restrict__ whhb,
    const float* __restrict__ bih, const float* __restrict__ bhh,
    const int* __restrict__ slotOf, u16* __restrict__ hb, float* __restrict__ cbuf,
    float* __restrict__ out, int K, int* __restrict__ bar) {
    __shared__ int sSlot[SM], sPrev[SM], sAux[SM];
    int jg = blockIdx.y;                    // 0..31 -> h-cols [jg*16, jg*16+16)
    int tid = threadIdx.x;
    int w = tid >> 6, l = tid & 63, u = l & 15, kg = l >> 4;
    int hc = jg * 16 + u;
    float bi = bih[hc] + bhh[hc];
    float bf_ = bih[HH + hc] + bhh[HH + hc];
    float bg = bih[2 * HH + hc] + bhh[2 * HH + hc];
    float bo = bih[3 * HH + hc] + bhh[3 * HH + hc];
    int gjv[4];
#pragma unroll
    for (int cb = 0; cb < 4; ++cb) gjv[cb] = cb * HH + hc;

    int iter = 0;
    for (int lev = 2; lev <= 9; ++lev) {
        int off, cap;
        buck_geom(2 + lev, CAP0, &off, &cap);
        int n = levelCount[2 + lev];
        if (n > cap) n = cap;
        int nt = (n + SM - 1) / SM;
        for (int mt = 0; mt < nt; ++mt) {
            int base = mt * SM;
            int nrow = min(SM, n - base);
            const int2* list = levelList + off + base;
            __syncthreads();
            if (tid < SM) {
                int2 e = list[(tid < nrow) ? tid : 0];
                int pos = e.x;
                sSlot[tid] = slotOf[pos];
                sPrev[tid] = slotOf[pos - 1];
                unsigned int y = (unsigned int)e.y;
                int grank = (int)(y & 0xFFFFu);
                sAux[tid] = (int)((y & 0x80000000u) |
                                  (unsigned int)(grank ? ((pos >> 10) * K + grank) : 0));
            }
            __syncthreads();
            int r0 = w * 16 + u;
            int xs0 = sSlot[r0], hp0 = sPrev[r0];
            f32x4 acc[4];
#pragma unroll
            for (int cb = 0; cb < 4; ++cb) acc[cb] = (f32x4)0.f;
            {
                const u16* a0 = xb + (size_t)xs0 * II;
#pragma unroll
                for (int s = 0; s < 4; ++s) {
                    int ko = s * 32 + kg * 8;
                    bf16x8 af0 = *(const bf16x8*)(a0 + ko);
#pragma unroll
                    for (int cb = 0; cb < 4; ++cb) {
                        bf16x8 bf = *(const bf16x8*)(wihb + (size_t)gjv[cb] * II + ko);
                        acc[cb] = __builtin_amdgcn_mfma_f32_16x16x32_bf16(af0, bf, acc[cb], 0, 0, 0);
                    }
                }
            }
            {
                const u16* a0 = hb + (size_t)hp0 * HH;
                for (int kc = 0; kc < 4; ++kc) {
#pragma unroll
                    for (int s = 0; s < 4; ++s) {
                        int ko = kc * 128 + s * 32 + kg * 8;
                        bf16x8 af0 = *(const bf16x8*)(a0 + ko);
#pragma unroll
                        for (int cb = 0; cb < 4; ++cb) {
                            bf16x8 bf = *(const bf16x8*)(whhb + (size_t)gjv[cb] * HH + ko);
                            acc[cb] = __builtin_amdgcn_mfma_f32_16x16x32_bf16(af0, bf, acc[cb], 0, 0, 0);
                        }
                    }
                }
            }
#pragma unroll
            for (int r = 0; r < 4; ++r) {
                int m = w * 16 + kg * 4 + r;
                if (m < nrow) {
                    int aux = sAux[m];
                    int oi = aux & 0x7FFFFFFF;
                    float gi = acc[0][r] + bi;
                    float gf = acc[1][r] + bf_;
                    float gg = acc[2][r] + bg;
                    float go = acc[3][r] + bo;
                    float cin = cbuf[(size_t)sPrev[m] * HH + hc];
                    float c2 = sigf(gf) * cin + sigf(gi) * tanhf(gg);
                    float h2 = sigf(go) * tanhf(c2);
                    if (oi) out[(size_t)(oi - 1) * HH + hc] = h2;
                    if (aux < 0) {
                        hb[(size_t)sSlot[m] * HH + hc] = f2b(h2);
                        cbuf[(size_t)sSlot[m] * HH + hc] = c2;
                    }
                }
            }
        }
        ++iter;
        if (lev < 9) {
            __threadfence();
            __syncthreads();
            if (tid == 0) {
                __hip_atomic_fetch_add(bar, 1, __ATOMIC_RELEASE, __HIP_MEMORY_SCOPE_AGENT);
                int target = 32 * iter;
                while (__hip_atomic_load(bar, __ATOMIC_ACQUIRE, __HIP_MEMORY_SCOPE_AGENT) < target) {
                    __builtin_amdgcn_s_sleep(1);
                }
            }
            __syncthreads();
            __threadfence();
        }
    }
}

// ---------------------------------------------------------------- launch
extern "C" void kernel_launch(void* const* d_in, const int* in_sizes, int n_in,
                              void* d_out, int out_size, void* d_ws, size_t ws_size,
                              hipStream_t stream) {
    const float* x    = (const float*)d_in[0];
    const int* mask   = (const int*)d_in[1];
    const int* length = (const int*)d_in[2];
    const float* Wih  = (const float*)d_in[3];
    const float* Whh  = (const float*)d_in[4];
    const float* bih  = (const float*)d_in[5];
    const float* bhh  = (const float*)d_in[6];
    float* out = (float*)d_out;

    int K = (out_size - BB) / (BB * HH);
    int R = K + 64;
    int SLOTS = BB * R;
    int CAP0 = SLOTS;

    char* basep = (char*)d_ws;
    size_t off = 0;
    auto take = [&](size_t bytes) -> char* {
        off = (off + 255) & ~(size_t)255;
        char* p = basep + off;
        off += bytes;
        return p;
    };
    int* slotOf      = (int*)take((size_t)BT * 4);
    int* levelCount  = (int*)take((NBUCK + 2) * 4);
    int2* levelList  = (int2*)take((size_t)(CAP0 + LIST_EXTRA) * 8);
    u16* xb          = (u16*)take((size_t)SLOTS * II * 2);
    u16* hb          = (u16*)take((size_t)SLOTS * HH * 2);
    float* cbuf      = (float*)take((size_t)SLOTS * HH * 4);
    u16* wihb        = (u16*)take((size_t)GG * II * 2);
    u16* whhb        = (u16*)take((size_t)GG * HH * 2);
    int* bar         = levelCount + NBUCK;
    (void)ws_size; (void)in_sizes; (void)n_in;

    k_wcvt<<<(GG * (II + HH) / 4 + 255) / 256, 256, 0, stream>>>(Wih, Whh, wihb, whhb, levelCount);
    k_prep<<<BB, 256, 0, stream>>>(mask, length, x, out + (size_t)BB * K * HH,
                                   levelCount, levelList, slotOf, xb, out, K, R, CAP0);

    int o2, c2g, o3, c3, o1, c1;
    buck_geom(2, CAP0, &o2, &c2g);
    buck_geom(3, CAP0, &o3, &c3);
    buck_geom(1, CAP0, &o1, &c1);

    // spine level 0 (K=128, writes hb/cbuf)
    k_gemm<0><<<dim3(c2g / BM, 16), 256, 0, stream>>>(
        2, o2, c2g, levelCount, levelList, xb, wihb, whhb, bih, bhh,
        slotOf, hb, cbuf, out, K);
    // spine level 1 (K=640)
    k_gemm<1><<<dim3(c3 / BM, 16), 256, 0, stream>>>(
        3, o3, c3, levelCount, levelList, xb, wihb, whhb, bih, bhh,
        slotOf, hb, cbuf, out, K);
    // spine levels 2..9 fused
    k_spineH<<<dim3(1, 32), 256, 0, stream>>>(
        CAP0, levelCount, levelList, xb, wihb, whhb, bih, bhh,
        slotOf, hb, cbuf, out, K, bar);
    // leaves with h (levels >=1), all parallel now
    k_gemm<1><<<dim3(c1 / BM, 16), 256, 0, stream>>>(
        1, o1, c1, levelCount, levelList, xb, wihb, whhb, bih, bhh,
        slotOf, hb, cbuf, out, K);
    // leaves at level 0 (the big one, K=128)
    k_gemm<0><<<dim3((CAP0 + BM - 1) / BM, 16), 256, 0, stream>>>(
        0, 0, CAP0, levelCount, levelList, xb, wihb, whhb, bih, bhh,
        slotOf, hb, cbuf, out, K);
}

// Round 7
// 125.094 us; speedup vs baseline: 1.7789x; 1.7789x over previous
//
#include <hip/hip_runtime.h>
#include <math.h>

#define BB 128
#define TT 1024
#define II 128
#define HH 512
#define GG 2048           // 4*H
#define BT (BB*TT)
#define LMAX 10
#define NBUCK 12          // 0:out0 leaves, 1:outH leaves, 2..11: spine lvl 0..9

#define BM 128            // rows per tile
#define BN 128            // gate cols per tile = 32 h-cols x 4 gates
#define KCH 128           // K chunk

typedef unsigned short u16;
typedef __attribute__((ext_vector_type(4))) u16 u16x4;
typedef __attribute__((ext_vector_type(8))) u16 u16x8;
typedef __attribute__((ext_vector_type(8))) short bf16x8;
typedef __attribute__((ext_vector_type(4))) float f32x4;

__device__ __forceinline__ float rcpf(float x) { return __builtin_amdgcn_rcpf(x); }
__device__ __forceinline__ float sigf(float v) { return rcpf(1.0f + __expf(-v)); }
__device__ __forceinline__ float tanhfast(float x) {
    float e = __expf(2.0f * x);
    return 1.0f - 2.0f * rcpf(e + 1.0f);
}

__device__ __forceinline__ u16 f2b(float f) {
    unsigned int x = __float_as_uint(f);
    return (u16)((x + 0x7fffu + ((x >> 16) & 1u)) >> 16);   // RNE, finite inputs
}

// bucket list geometry
__host__ __device__ __forceinline__ void buck_geom(int bkt, int CAP0, int* off, int* cap) {
    if (bkt == 0) { *off = 0; *cap = CAP0; return; }
    int o = CAP0;
    if (bkt == 1) { *off = o; *cap = 2048; return; } o += 2048;  // outH leaves
    if (bkt == 2) { *off = o; *cap = 2048; return; } o += 2048;  // spine lvl0
    if (bkt == 3) { *off = o; *cap = 512;  return; } o += 512;   // spine lvl1
    if (bkt == 4) { *off = o; *cap = 128;  return; } o += 128;   // spine lvl2
    *off = o + (bkt - 5) * 64; *cap = 64;                         // spine lvl3..9
}
#define LIST_EXTRA (2048 + 2048 + 512 + 128 + 7*64)

__device__ __forceinline__ int block_scan_excl(int* scan, int tid, int v, int* total) {
    scan[tid] = v;
    __syncthreads();
    for (int s = 1; s < 256; s <<= 1) {
        int a = scan[tid];
        int u = (tid >= s) ? scan[tid - s] : 0;
        __syncthreads();
        scan[tid] = a + u;
        __syncthreads();
    }
    int incl = scan[tid];
    *total = scan[255];
    __syncthreads();
    return incl - v;
}

// ---------------------------------------------------------------- k_wcvt
__global__ void k_wcvt(const float* __restrict__ Wih, const float* __restrict__ Whh,
                       u16* __restrict__ wihb, u16* __restrict__ whhb,
                       int* __restrict__ levelCount) {
    if (blockIdx.x == 0 && threadIdx.x < NBUCK) levelCount[threadIdx.x] = 0;
    int i = blockIdx.x * 256 + threadIdx.x;
    const int NW = GG * II / 4;
    const int NH = GG * HH / 4;
    if (i < NW) {
        float4 v = ((const float4*)Wih)[i];
        u16x4 u = { f2b(v.x), f2b(v.y), f2b(v.z), f2b(v.w) };
        ((u16x4*)wihb)[i] = u;
    } else if (i < NW + NH) {
        int j = i - NW;
        float4 v = ((const float4*)Whh)[j];
        u16x4 u = { f2b(v.x), f2b(v.y), f2b(v.z), f2b(v.w) };
        ((u16x4*)whhb)[j] = u;
    }
}

// ---------------------------------------------------------------- k_prep
__global__ __launch_bounds__(256) void k_prep(
    const int* __restrict__ mask, const int* __restrict__ length,
    const float* __restrict__ x, float* __restrict__ wnOut,
    int* __restrict__ levelCount, int2* __restrict__ levelList,
    int* __restrict__ slotOf, u16* __restrict__ xb, float* __restrict__ out,
    int K, int R, int CAP0) {
    __shared__ unsigned char sm[TT];
    __shared__ unsigned char sne[TT];
    __shared__ u16 sgp[TT];
    __shared__ int scan[256];
    __shared__ int cnt[NBUCK], cnt2[NBUCK], bas[NBUCK];
    __shared__ u16 spos[256];
    __shared__ u16 zlist[256];
    __shared__ int zn;

    int b = blockIdx.x, tid = threadIdx.x;
    int len = length[b];
    int t0 = tid * 4;
    if (tid == 0) zn = 0;

    int4 mk = ((const int4*)(mask + (size_t)b * TT))[tid];
    int mraw[4] = { mk.x, mk.y, mk.z, mk.w };
    unsigned char mv[4];
    int lzero = 0;
#pragma unroll
    for (int j = 0; j < 4; ++j) {
        int t = t0 + j;
        unsigned char m = (t == len - 1) ? 1 : ((t == 0) ? 0 : (mraw[j] != 0));
        mv[j] = m;
        sm[t] = m;
        sgp[t] = 0;
        lzero += !m;
    }

    int Z;
    int zbase = block_scan_excl(scan, tid, lzero, &Z);
    int wn = TT - Z;
    if (tid == 0) wnOut[b] = (float)wn;
    int need = K - wn;

    int psel[4];
    int lpad = 0;
    {
        int zb = zbase;
#pragma unroll
        for (int j = 0; j < 4; ++j) {
            int sel = mv[j] | ((Z - zb) <= need ? 1 : 0);
            psel[j] = sel;
            lpad += sel;
            zb += !mv[j];
        }
    }
    int ptot;
    int pbase = block_scan_excl(scan, tid, lpad, &ptot);
    {
        int k = pbase;
#pragma unroll
        for (int j = 0; j < 4; ++j) {
            int t = t0 + j;
            if (psel[j]) {
                sgp[t - 1] = (u16)(k + 1);          // t==0 never selected (K << T)
                if (t - 1 >= len) {                 // inactive source -> zero out row
                    int zi = atomicAdd(&zn, 1);
                    if (zi < 256) zlist[zi] = (u16)k;
                }
                ++k;
            }
        }
    }
    __syncthreads();

    // needed (short forward chain walk) + chain level
    int nev[4], lvlv[4];
    int lne = 0;
#pragma unroll
    for (int j = 0; j < 4; ++j) {
        int t = t0 + j;
        int ne = 0;
        if (t < len) {
            int tt = t;
            ne = sgp[tt] != 0;
            while (!ne && tt + 1 < TT && tt + 1 < len && sm[tt + 1]) { ++tt; ne = sgp[tt] != 0; }
        }
        nev[j] = ne;
        sne[t] = (unsigned char)ne;
        lne += ne;
        int l = 0;
        if (mv[j]) { int tt = t; while (tt >= 0 && sm[tt] && l < LMAX - 1) { ++l; --tt; } }
        lvlv[j] = l;
    }

    int ntot;
    int nbase = block_scan_excl(scan, tid, lne, &ntot);   // syncs inside; sne visible
    {
        int r = nbase;
        int sv[4];
#pragma unroll
        for (int j = 0; j < 4; ++j) {
            if (nev[j]) { sv[j] = b * R + r; if (r < 256) spos[r] = (u16)(t0 + j); }
            else sv[j] = -1;
            r += nev[j];
        }
        *(int4*)(slotOf + (size_t)b * TT + t0) = make_int4(sv[0], sv[1], sv[2], sv[3]);
    }

    if (tid < NBUCK) { cnt[tid] = 0; cnt2[tid] = 0; }
    __syncthreads();
    int bktv[4];
#pragma unroll
    for (int j = 0; j < 4; ++j) {
        bktv[j] = -1;
        if (nev[j]) {
            int t = t0 + j;
            int pred = (t + 1 < TT) && sm[t + 1] && sne[t + 1];
            int bkt = pred ? (2 + lvlv[j]) : (lvlv[j] ? 1 : 0);
            bktv[j] = bkt;
            atomicAdd(&cnt[bkt], 1);
        }
    }
    __syncthreads();
    if (tid < NBUCK) bas[tid] = cnt[tid] ? atomicAdd(&levelCount[tid], cnt[tid]) : 0;
    __syncthreads();
#pragma unroll
    for (int j = 0; j < 4; ++j) if (nev[j]) {
        int t = t0 + j;
        int bkt = bktv[j];
        int r = atomicAdd(&cnt2[bkt], 1);
        int off, cap;
        buck_geom(bkt, CAP0, &off, &cap);
        int idx = bas[bkt] + r;
        unsigned int y = ((bkt >= 2) ? 0x80000000u : 0u) | (unsigned int)sgp[t];
        if (idx < cap) levelList[off + idx] = make_int2(b * TT + t, (int)y);
    }
    __syncthreads();

    // x rows of needed slots -> bf16
    int nv = (ntot < 256 ? ntot : 256) * 16;
    for (int idx = tid; idx < nv; idx += 256) {
        int r = idx >> 4, part = idx & 15;
        int t = spos[r];
        const float* src = x + ((size_t)b * TT + t) * II + part * 8;
        float4 v0 = ((const float4*)src)[0];
        float4 v1 = ((const float4*)src)[1];
        u16x8 u = { f2b(v0.x), f2b(v0.y), f2b(v0.z), f2b(v0.w),
                    f2b(v1.x), f2b(v1.y), f2b(v1.z), f2b(v1.w) };
        *(u16x8*)(xb + ((size_t)b * R + r) * II + part * 8) = u;
    }
    // zero gather rows with inactive sources
    int znv = zn < 256 ? zn : 256;
    for (int idx = tid; idx < znv * 128; idx += 256) {
        int e = idx >> 7, q = idx & 127;
        ((float4*)(out + ((size_t)b * K + zlist[e]) * HH))[q] = make_float4(0.f, 0.f, 0.f, 0.f);
    }
}

// ---------------------------------------------------------------- k_gemm (LDS-staged MFMA)
// BM=128 rows x BN=128 gate cols per block; LDS XOR-swizzled tiles.
template<int HASH>
__global__ __launch_bounds__(256) void k_gemm(
    int cntIdx, int listOff, int cap,
    const int* __restrict__ levelCount, const int2* __restrict__ levelList,
    const u16* __restrict__ xb, const u16* __restrict__ wihb, const u16* __restrict__ whhb,
    const float* __restrict__ bih, const float* __restrict__ bhh,
    const int* __restrict__ slotOf, u16* __restrict__ hb, float* __restrict__ cbuf,
    float* __restrict__ out, int K) {
    int n = levelCount[cntIdx];
    if (n > cap) n = cap;
    int nt = (n + BM - 1) / BM;
    if ((int)blockIdx.x >= nt) return;
    int base = blockIdx.x * BM;
    int nrow = min(BM, n - base);
    int jg = blockIdx.y;                       // 0..15 -> h-cols [jg*32, jg*32+32)
    const int2* list = levelList + listOff + base;

    __shared__ u16 As[BM * KCH];               // [row][k], swizzled, 256B/row
    __shared__ u16 Bs[BN * KCH];
    __shared__ int sSlot[BM], sPrev[BM], sAux[BM];

    int tid = threadIdx.x;
    if (tid < BM) {
        int2 e = list[(tid < nrow) ? tid : 0];
        int pos = e.x;
        sSlot[tid] = slotOf[pos];
        sPrev[tid] = HASH ? slotOf[pos - 1] : 0;
        unsigned int y = (unsigned int)e.y;
        int grank = (int)(y & 0xFFFFu);
        sAux[tid] = (int)((y & 0x80000000u) | (unsigned int)(grank ? ((pos >> 10) * K + grank) : 0));
    }
    __syncthreads();

    int w = tid >> 6, l = tid & 63;
    f32x4 acc[2][8];
#pragma unroll
    for (int rb = 0; rb < 2; ++rb)
#pragma unroll
        for (int cb = 0; cb < 8; ++cb) acc[rb][cb] = (f32x4)0.f;

    const int nch = HASH ? 5 : 1;              // K chunks of 128
    for (int kc = 0; kc < nch; ++kc) {
        bool fromX = (kc == 0);
        int row = tid >> 1, half = tid & 1;
        // stage A (128 rows x 128 k bf16)
        {
            const u16* src = (fromX ? (xb + (size_t)sSlot[row] * II)
                                    : (hb + (size_t)sPrev[row] * HH + (kc * KCH - II))) + half * 64;
            int swz = (row & 7) << 4;
#pragma unroll
            for (int i = 0; i < 8; ++i) {
                int e2 = half * 128 + i * 16;
                u16x8 v = *(const u16x8*)(src + i * 8);
                *(u16x8*)((char*)As + row * 256 + (e2 ^ swz)) = v;
            }
        }
        // stage B (128 gate cols x 128 k); col r -> gj = (r>>5)*HH + jg*32 + (r&31)
        {
            int gj = (row >> 5) * HH + jg * 32 + (row & 31);
            const u16* src = (fromX ? (wihb + (size_t)gj * II)
                                    : (whhb + (size_t)gj * HH + (kc * KCH - II))) + half * 64;
            int swz = (row & 7) << 4;
#pragma unroll
            for (int i = 0; i < 8; ++i) {
                int e2 = half * 128 + i * 16;
                u16x8 v = *(const u16x8*)(src + i * 8);
                *(u16x8*)((char*)Bs + row * 256 + (e2 ^ swz)) = v;
            }
        }
        __syncthreads();
#pragma unroll
        for (int s = 0; s < 4; ++s) {
            bf16x8 af[2], bfr[8];
#pragma unroll
            for (int rb = 0; rb < 2; ++rb) {
                int rr = w * 32 + rb * 16 + (l & 15);
                int byte = rr * 256 + ((s * 64 + (l >> 4) * 16) ^ ((rr & 7) << 4));
                af[rb] = *(const bf16x8*)((const char*)As + byte);
            }
#pragma unroll
            for (int cb = 0; cb < 8; ++cb) {
                int rr = cb * 16 + (l & 15);
                int byte = rr * 256 + ((s * 64 + (l >> 4) * 16) ^ ((rr & 7) << 4));
                bfr[cb] = *(const bf16x8*)((const char*)Bs + byte);
            }
#pragma unroll
            for (int rb = 0; rb < 2; ++rb)
#pragma unroll
                for (int cb = 0; cb < 8; ++cb)
                    acc[rb][cb] = __builtin_amdgcn_mfma_f32_16x16x32_bf16(
                        af[rb], bfr[cb], acc[rb][cb], 0, 0, 0);
        }
        __syncthreads();
    }

    // epilogue: lane covers 2 h-cols (h0, h0+16) x 4 gates
    int u = l & 15;
    int h0 = jg * 32 + u;
    float b_i[2], b_f[2], b_g[2], b_o[2];
#pragma unroll
    for (int h = 0; h < 2; ++h) {
        int hc = h0 + h * 16;
        b_i[h] = bih[hc] + bhh[hc];
        b_f[h] = bih[HH + hc] + bhh[HH + hc];
        b_g[h] = bih[2 * HH + hc] + bhh[2 * HH + hc];
        b_o[h] = bih[3 * HH + hc] + bhh[3 * HH + hc];
    }
#pragma unroll
    for (int rb = 0; rb < 2; ++rb) {
#pragma unroll
        for (int r = 0; r < 4; ++r) {
            int m = w * 32 + rb * 16 + (l >> 4) * 4 + r;
            if (m < nrow) {
                int aux = sAux[m];
                int oi = aux & 0x7FFFFFFF;
                int sp = HASH ? sPrev[m] : 0;
                int sl = sSlot[m];
#pragma unroll
                for (int h = 0; h < 2; ++h) {
                    int hc = h0 + h * 16;
                    float gi = acc[rb][0 + h][r] + b_i[h];
                    float gf = acc[rb][2 + h][r] + b_f[h];
                    float gg = acc[rb][4 + h][r] + b_g[h];
                    float go = acc[rb][6 + h][r] + b_o[h];
                    float cin = HASH ? cbuf[(size_t)sp * HH + hc] : 0.f;
                    float c2 = sigf(gf) * cin + sigf(gi) * tanhfast(gg);
                    float h2 = sigf(go) * tanhfast(c2);
                    if (oi) out[(size_t)(oi - 1) * HH + hc] = h2;
                    if (aux < 0) {                      // spine: feed next level
                        hb[(size_t)sl * HH + hc] = f2b(h2);
                        cbuf[(size_t)sl * HH + hc] = c2;
                    }
                }
            }
        }
    }
}

// ---------------------------------------------------------------- launch
extern "C" void kernel_launch(void* const* d_in, const int* in_sizes, int n_in,
                              void* d_out, int out_size, void* d_ws, size_t ws_size,
                              hipStream_t stream) {
    const float* x    = (const float*)d_in[0];
    const int* mask   = (const int*)d_in[1];
    const int* length = (const int*)d_in[2];
    const float* Wih  = (const float*)d_in[3];
    const float* Whh  = (const float*)d_in[4];
    const float* bih  = (const float*)d_in[5];
    const float* bhh  = (const float*)d_in[6];
    float* out = (float*)d_out;

    int K = (out_size - BB) / (BB * HH);
    int R = K + 64;
    int SLOTS = BB * R;
    int CAP0 = SLOTS;

    char* basep = (char*)d_ws;
    size_t off = 0;
    auto take = [&](size_t bytes) -> char* {
        off = (off + 255) & ~(size_t)255;
        char* p = basep + off;
        off += bytes;
        return p;
    };
    int* slotOf      = (int*)take((size_t)BT * 4);
    int* levelCount  = (int*)take(NBUCK * 4);
    int2* levelList  = (int2*)take((size_t)(CAP0 + LIST_EXTRA) * 8);
    u16* xb          = (u16*)take((size_t)SLOTS * II * 2);
    u16* hb          = (u16*)take((size_t)SLOTS * HH * 2);
    float* cbuf      = (float*)take((size_t)SLOTS * HH * 4);
    u16* wihb        = (u16*)take((size_t)GG * II * 2);
    u16* whhb        = (u16*)take((size_t)GG * HH * 2);
    (void)ws_size; (void)in_sizes; (void)n_in;

    k_wcvt<<<(GG * (II + HH) / 4 + 255) / 256, 256, 0, stream>>>(Wih, Whh, wihb, whhb, levelCount);
    k_prep<<<BB, 256, 0, stream>>>(mask, length, x, out + (size_t)BB * K * HH,
                                   levelCount, levelList, slotOf, xb, out, K, R, CAP0);

    int off_, cap_;
    // spine level 0 (K=128, writes hb/cbuf)
    buck_geom(2, CAP0, &off_, &cap_);
    k_gemm<0><<<dim3(cap_ / BM, GG / BN), 256, 0, stream>>>(
        2, off_, cap_, levelCount, levelList, xb, wihb, whhb, bih, bhh,
        slotOf, hb, cbuf, out, K);
    // spine level 1 (K=640)
    buck_geom(3, CAP0, &off_, &cap_);
    k_gemm<1><<<dim3(cap_ / BM, GG / BN), 256, 0, stream>>>(
        3, off_, cap_, levelCount, levelList, xb, wihb, whhb, bih, bhh,
        slotOf, hb, cbuf, out, K);
    // spine levels 2..9: tiny launches, early-exit when empty
    for (int lev = 2; lev <= 9; ++lev) {
        buck_geom(2 + lev, CAP0, &off_, &cap_);
        k_gemm<1><<<dim3(1, GG / BN), 256, 0, stream>>>(
            2 + lev, off_, cap_, levelCount, levelList, xb, wihb, whhb, bih, bhh,
            slotOf, hb, cbuf, out, K);
    }
    // leaves with h (levels >=1), all parallel after spine
    buck_geom(1, CAP0, &off_, &cap_);
    k_gemm<1><<<dim3(cap_ / BM, GG / BN), 256, 0, stream>>>(
        1, off_, cap_, levelCount, levelList, xb, wihb, whhb, bih, bhh,
        slotOf, hb, cbuf, out, K);
    // leaves at level 0 (the big one, K=128)
    k_gemm<0><<<dim3((CAP0 + BM - 1) / BM, GG / BN), 256, 0, stream>>>(
        0, 0, CAP0, levelCount, levelList, xb, wihb, whhb, bih, bhh,
        slotOf, hb, cbuf, out, K);
}

// Round 8
// 97.813 us; speedup vs baseline: 2.2750x; 1.2789x over previous
//
#include <hip/hip_runtime.h>
#include <math.h>

#define BB 128
#define TT 1024
#define II 128
#define HH 512
#define GG 2048           // 4*H
#define BT (BB*TT)
#define LMAX 10
#define NBUCK 12          // 0:out0 leaves, 1:outH leaves, 2..11: spine lvl 0..9

#define BM 128            // rows per tile
#define BN 128            // gate cols per tile = 32 h-cols x 4 gates
#define KCH 128           // K chunk

typedef unsigned short u16;
typedef __attribute__((ext_vector_type(4))) u16 u16x4;
typedef __attribute__((ext_vector_type(8))) u16 u16x8;
typedef __attribute__((ext_vector_type(8))) short bf16x8;
typedef __attribute__((ext_vector_type(4))) float f32x4;

typedef __attribute__((address_space(3))) unsigned int lds_u32;
typedef __attribute__((address_space(1))) const unsigned int gbl_u32;

__device__ __forceinline__ void gload16(const void* g, void* l) {
    __builtin_amdgcn_global_load_lds((gbl_u32*)g, (lds_u32*)l, 16, 0, 0);
}

__device__ __forceinline__ float rcpf(float x) { return __builtin_amdgcn_rcpf(x); }
__device__ __forceinline__ float sigf(float v) { return rcpf(1.0f + __expf(-v)); }
__device__ __forceinline__ float tanhfast(float x) {
    float e = __expf(2.0f * x);
    return 1.0f - 2.0f * rcpf(e + 1.0f);
}

__device__ __forceinline__ u16 f2b(float f) {
    unsigned int x = __float_as_uint(f);
    return (u16)((x + 0x7fffu + ((x >> 16) & 1u)) >> 16);   // RNE, finite inputs
}

// bucket list geometry
__host__ __device__ __forceinline__ void buck_geom(int bkt, int CAP0, int* off, int* cap) {
    if (bkt == 0) { *off = 0; *cap = CAP0; return; }
    int o = CAP0;
    if (bkt == 1) { *off = o; *cap = 2048; return; } o += 2048;  // outH leaves
    if (bkt == 2) { *off = o; *cap = 2048; return; } o += 2048;  // spine lvl0
    if (bkt == 3) { *off = o; *cap = 512;  return; } o += 512;   // spine lvl1
    if (bkt == 4) { *off = o; *cap = 128;  return; } o += 128;   // spine lvl2
    *off = o + (bkt - 5) * 64; *cap = 64;                         // spine lvl3..9
}
#define LIST_EXTRA (2048 + 2048 + 512 + 128 + 7*64)

// wave-shuffle block scan (2 syncs instead of 16)
__device__ __forceinline__ int block_scan_excl(int* ws4, int tid, int v, int* total) {
    int lane = tid & 63, wv = tid >> 6;
    int incl = v;
#pragma unroll
    for (int s = 1; s < 64; s <<= 1) {
        int u = __shfl_up(incl, (unsigned)s, 64);
        if (lane >= s) incl += u;
    }
    __syncthreads();                  // protect ws4 reuse across calls
    if (lane == 63) ws4[wv] = incl;
    __syncthreads();
    int base = 0, tot = 0;
#pragma unroll
    for (int i = 0; i < 4; ++i) { int t = ws4[i]; if (i < wv) base += t; tot += t; }
    *total = tot;
    return base + incl - v;
}

// ---------------------------------------------------------------- k_wcvt
__global__ void k_wcvt(const float* __restrict__ Wih, const float* __restrict__ Whh,
                       u16* __restrict__ wihb, u16* __restrict__ whhb,
                       int* __restrict__ levelCount) {
    if (blockIdx.x == 0 && threadIdx.x < NBUCK) levelCount[threadIdx.x] = 0;
    int i = blockIdx.x * 256 + threadIdx.x;
    const int NW = GG * II / 4;
    const int NH = GG * HH / 4;
    if (i < NW) {
        float4 v = ((const float4*)Wih)[i];
        u16x4 u = { f2b(v.x), f2b(v.y), f2b(v.z), f2b(v.w) };
        ((u16x4*)wihb)[i] = u;
    } else if (i < NW + NH) {
        int j = i - NW;
        float4 v = ((const float4*)Whh)[j];
        u16x4 u = { f2b(v.x), f2b(v.y), f2b(v.z), f2b(v.w) };
        ((u16x4*)whhb)[j] = u;
    }
}

// ---------------------------------------------------------------- k_prep
__global__ __launch_bounds__(256) void k_prep(
    const int* __restrict__ mask, const int* __restrict__ length,
    const float* __restrict__ x, float* __restrict__ wnOut,
    int* __restrict__ levelCount, int2* __restrict__ levelList,
    int* __restrict__ slotOf, u16* __restrict__ xb, float* __restrict__ out,
    int K, int R, int CAP0) {
    __shared__ unsigned char sm[TT];
    __shared__ unsigned char sne[TT];
    __shared__ u16 sgp[TT];
    __shared__ int ws4[4];
    __shared__ int cnt[NBUCK], cnt2[NBUCK], bas[NBUCK];
    __shared__ u16 spos[256];
    __shared__ u16 zlist[256];
    __shared__ int zn;

    int b = blockIdx.x, tid = threadIdx.x;
    int len = length[b];
    int t0 = tid * 4;
    if (tid == 0) zn = 0;

    int4 mk = ((const int4*)(mask + (size_t)b * TT))[tid];
    int mraw[4] = { mk.x, mk.y, mk.z, mk.w };
    unsigned char mv[4];
    int lzero = 0;
#pragma unroll
    for (int j = 0; j < 4; ++j) {
        int t = t0 + j;
        unsigned char m = (t == len - 1) ? 1 : ((t == 0) ? 0 : (mraw[j] != 0));
        mv[j] = m;
        sm[t] = m;
        sgp[t] = 0;
        lzero += !m;
    }

    int Z;
    int zbase = block_scan_excl(ws4, tid, lzero, &Z);
    int wn = TT - Z;
    if (tid == 0) wnOut[b] = (float)wn;
    int need = K - wn;

    int psel[4];
    int lpad = 0;
    {
        int zb = zbase;
#pragma unroll
        for (int j = 0; j < 4; ++j) {
            int sel = mv[j] | ((Z - zb) <= need ? 1 : 0);
            psel[j] = sel;
            lpad += sel;
            zb += !mv[j];
        }
    }
    int ptot;
    int pbase = block_scan_excl(ws4, tid, lpad, &ptot);
    {
        int k = pbase;
#pragma unroll
        for (int j = 0; j < 4; ++j) {
            int t = t0 + j;
            if (psel[j]) {
                sgp[t - 1] = (u16)(k + 1);          // t==0 never selected (K << T)
                if (t - 1 >= len) {                 // inactive source -> zero out row
                    int zi = atomicAdd(&zn, 1);
                    if (zi < 256) zlist[zi] = (u16)k;
                }
                ++k;
            }
        }
    }
    __syncthreads();

    // needed (short forward chain walk) + chain level
    int nev[4], lvlv[4];
    int lne = 0;
#pragma unroll
    for (int j = 0; j < 4; ++j) {
        int t = t0 + j;
        int ne = 0;
        if (t < len) {
            int tt = t;
            ne = sgp[tt] != 0;
            while (!ne && tt + 1 < TT && tt + 1 < len && sm[tt + 1]) { ++tt; ne = sgp[tt] != 0; }
        }
        nev[j] = ne;
        sne[t] = (unsigned char)ne;
        lne += ne;
        int l = 0;
        if (mv[j]) { int tt = t; while (tt >= 0 && sm[tt] && l < LMAX - 1) { ++l; --tt; } }
        lvlv[j] = l;
    }

    int ntot;
    int nbase = block_scan_excl(ws4, tid, lne, &ntot);   // syncs inside; sne visible
    {
        int r = nbase;
        int sv[4];
#pragma unroll
        for (int j = 0; j < 4; ++j) {
            if (nev[j]) { sv[j] = b * R + r; if (r < 256) spos[r] = (u16)(t0 + j); }
            else sv[j] = -1;
            r += nev[j];
        }
        *(int4*)(slotOf + (size_t)b * TT + t0) = make_int4(sv[0], sv[1], sv[2], sv[3]);
    }

    if (tid < NBUCK) { cnt[tid] = 0; cnt2[tid] = 0; }
    __syncthreads();
    int bktv[4];
#pragma unroll
    for (int j = 0; j < 4; ++j) {
        bktv[j] = -1;
        if (nev[j]) {
            int t = t0 + j;
            int pred = (t + 1 < TT) && sm[t + 1] && sne[t + 1];
            int bkt = pred ? (2 + lvlv[j]) : (lvlv[j] ? 1 : 0);
            bktv[j] = bkt;
            atomicAdd(&cnt[bkt], 1);
        }
    }
    __syncthreads();
    if (tid < NBUCK) bas[tid] = cnt[tid] ? atomicAdd(&levelCount[tid], cnt[tid]) : 0;
    __syncthreads();
#pragma unroll
    for (int j = 0; j < 4; ++j) if (nev[j]) {
        int t = t0 + j;
        int bkt = bktv[j];
        int r = atomicAdd(&cnt2[bkt], 1);
        int off, cap;
        buck_geom(bkt, CAP0, &off, &cap);
        int idx = bas[bkt] + r;
        unsigned int y = ((bkt >= 2) ? 0x80000000u : 0u) | (unsigned int)sgp[t];
        if (idx < cap) levelList[off + idx] = make_int2(b * TT + t, (int)y);
    }
    __syncthreads();

    // x rows of needed slots -> bf16
    int nv = (ntot < 256 ? ntot : 256) * 16;
    for (int idx = tid; idx < nv; idx += 256) {
        int r = idx >> 4, part = idx & 15;
        int t = spos[r];
        const float* src = x + ((size_t)b * TT + t) * II + part * 8;
        float4 v0 = ((const float4*)src)[0];
        float4 v1 = ((const float4*)src)[1];
        u16x8 u = { f2b(v0.x), f2b(v0.y), f2b(v0.z), f2b(v0.w),
                    f2b(v1.x), f2b(v1.y), f2b(v1.z), f2b(v1.w) };
        *(u16x8*)(xb + ((size_t)b * R + r) * II + part * 8) = u;
    }
    // zero gather rows with inactive sources
    int znv = zn < 256 ? zn : 256;
    for (int idx = tid; idx < znv * 128; idx += 256) {
        int e = idx >> 7, q = idx & 127;
        ((float4*)(out + ((size_t)b * K + zlist[e]) * HH))[q] = make_float4(0.f, 0.f, 0.f, 0.f);
    }
}

// ---------------------------------------------------------------- gemm tile (device)
// LDS layout: linear dest via global_load_lds; source pre-inverse-swizzled so that
// LDS (row, byte c) holds source byte (c ^ ((row&7)<<4)); reads swizzle identically.
template<int HASH>
__device__ __forceinline__ void gemm_tile(
    const int2* __restrict__ list, int nrow, int jg,
    const u16* __restrict__ xb, const u16* __restrict__ wihb, const u16* __restrict__ whhb,
    const float* __restrict__ bih, const float* __restrict__ bhh,
    const int* __restrict__ slotOf, u16* __restrict__ hb, float* __restrict__ cbuf,
    float* __restrict__ out, int K,
    u16* As, u16* Bs, int* sSlot, int* sPrev, int* sAux) {
    int tid = threadIdx.x;
    if (tid < BM) {
        int2 e = list[(tid < nrow) ? tid : 0];
        int pos = e.x;
        sSlot[tid] = slotOf[pos];
        sPrev[tid] = HASH ? slotOf[pos - 1] : 0;
        unsigned int y = (unsigned int)e.y;
        int grank = (int)(y & 0xFFFFu);
        sAux[tid] = (int)((y & 0x80000000u) | (unsigned int)(grank ? ((pos >> 10) * K + grank) : 0));
    }
    __syncthreads();

    int w = tid >> 6, l = tid & 63;
    int lrow = l >> 4;                 // row within a 1KB (4-row) DMA span
    int cbyte = (l & 15) << 4;         // 16B chunk within the 256B row
    f32x4 acc[2][8];
#pragma unroll
    for (int rb = 0; rb < 2; ++rb)
#pragma unroll
        for (int cb = 0; cb < 8; ++cb) acc[rb][cb] = (f32x4)0.f;

    const int nch = HASH ? 5 : 1;      // K chunks of 128
    for (int kc = 0; kc < nch; ++kc) {
        bool fromX = (kc == 0);
        int koff = kc * KCH - II;      // u16 offset into h rows (used when kc>=1)
        // stage A+B via global_load_lds: wave w, issue i -> LDS rows w*32+i*4..+3
#pragma unroll
        for (int i = 0; i < 8; ++i) {
            int rr = (w << 5) + (i << 2) + lrow;
            int so = cbyte ^ ((rr & 7) << 4);
            const char* srcA = fromX
                ? (const char*)(xb + (size_t)sSlot[rr] * II) + so
                : (const char*)(hb + (size_t)sPrev[rr] * HH + koff) + so;
            gload16(srcA, (char*)As + (w << 13) + (i << 10));
            int gj = (rr >> 5) * HH + jg * 32 + (rr & 31);
            const char* srcB = fromX
                ? (const char*)(wihb + (size_t)gj * II) + so
                : (const char*)(whhb + (size_t)gj * HH + koff) + so;
            gload16(srcB, (char*)Bs + (w << 13) + (i << 10));
        }
        __syncthreads();               // compiler drains vmcnt(0) before s_barrier
#pragma unroll
        for (int s = 0; s < 4; ++s) {
            bf16x8 af[2], bfr[8];
#pragma unroll
            for (int rb = 0; rb < 2; ++rb) {
                int rr = w * 32 + rb * 16 + (l & 15);
                int byte = rr * 256 + ((s * 64 + (l >> 4) * 16) ^ ((rr & 7) << 4));
                af[rb] = *(const bf16x8*)((const char*)As + byte);
            }
#pragma unroll
            for (int cb = 0; cb < 8; ++cb) {
                int rr = cb * 16 + (l & 15);
                int byte = rr * 256 + ((s * 64 + (l >> 4) * 16) ^ ((rr & 7) << 4));
                bfr[cb] = *(const bf16x8*)((const char*)Bs + byte);
            }
#pragma unroll
            for (int rb = 0; rb < 2; ++rb)
#pragma unroll
                for (int cb = 0; cb < 8; ++cb)
                    acc[rb][cb] = __builtin_amdgcn_mfma_f32_16x16x32_bf16(
                        af[rb], bfr[cb], acc[rb][cb], 0, 0, 0);
        }
        __syncthreads();
    }

    // epilogue: lane covers 2 h-cols (h0, h0+16) x 4 gates
    int u = l & 15;
    int h0 = jg * 32 + u;
    float b_i[2], b_f[2], b_g[2], b_o[2];
#pragma unroll
    for (int h = 0; h < 2; ++h) {
        int hc = h0 + h * 16;
        b_i[h] = bih[hc] + bhh[hc];
        b_f[h] = bih[HH + hc] + bhh[HH + hc];
        b_g[h] = bih[2 * HH + hc] + bhh[2 * HH + hc];
        b_o[h] = bih[3 * HH + hc] + bhh[3 * HH + hc];
    }
#pragma unroll
    for (int rb = 0; rb < 2; ++rb) {
#pragma unroll
        for (int r = 0; r < 4; ++r) {
            int m = w * 32 + rb * 16 + (l >> 4) * 4 + r;
            if (m < nrow) {
                int aux = sAux[m];
                int oi = aux & 0x7FFFFFFF;
                int sp = HASH ? sPrev[m] : 0;
                int sl = sSlot[m];
#pragma unroll
                for (int h = 0; h < 2; ++h) {
                    int hc = h0 + h * 16;
                    float gi = acc[rb][0 + h][r] + b_i[h];
                    float gf = acc[rb][2 + h][r] + b_f[h];
                    float gg = acc[rb][4 + h][r] + b_g[h];
                    float go = acc[rb][6 + h][r] + b_o[h];
                    float cin = HASH ? cbuf[(size_t)sp * HH + hc] : 0.f;
                    float c2 = sigf(gf) * cin + sigf(gi) * tanhfast(gg);
                    float h2 = sigf(go) * tanhfast(c2);
                    if (oi) out[(size_t)(oi - 1) * HH + hc] = h2;
                    if (aux < 0) {                      // spine: feed next level
                        hb[(size_t)sl * HH + hc] = f2b(h2);
                        cbuf[(size_t)sl * HH + hc] = c2;
                    }
                }
            }
        }
    }
}

// ---------------------------------------------------------------- k_gemm (generic bucket)
template<int HASH>
__global__ __launch_bounds__(256) void k_gemm(
    int cntIdx, int listOff, int cap,
    const int* __restrict__ levelCount, const int2* __restrict__ levelList,
    const u16* __restrict__ xb, const u16* __restrict__ wihb, const u16* __restrict__ whhb,
    const float* __restrict__ bih, const float* __restrict__ bhh,
    const int* __restrict__ slotOf, u16* __restrict__ hb, float* __restrict__ cbuf,
    float* __restrict__ out, int K) {
    __shared__ __align__(16) u16 As[BM * KCH];
    __shared__ __align__(16) u16 Bs[BN * KCH];
    __shared__ int sSlot[BM], sPrev[BM], sAux[BM];
    int n = levelCount[cntIdx];
    if (n > cap) n = cap;
    int base = blockIdx.x * BM;
    if (base >= n) return;
    gemm_tile<HASH>(levelList + listOff + base, min(BM, n - base), blockIdx.y,
                    xb, wihb, whhb, bih, bhh, slotOf, hb, cbuf, out, K,
                    As, Bs, sSlot, sPrev, sAux);
}

// ---------------------------------------------------------------- k_big0 (spine0 + leaves0)
// both HASH=0, both depend only on prep; first ntS tiles = spine0, rest = leaves0.
__global__ __launch_bounds__(256) void k_big0(
    int offS, int capS, int CAP0,
    const int* __restrict__ levelCount, const int2* __restrict__ levelList,
    const u16* __restrict__ xb, const u16* __restrict__ wihb, const u16* __restrict__ whhb,
    const float* __restrict__ bih, const float* __restrict__ bhh,
    const int* __restrict__ slotOf, u16* __restrict__ hb, float* __restrict__ cbuf,
    float* __restrict__ out, int K) {
    __shared__ __align__(16) u16 As[BM * KCH];
    __shared__ __align__(16) u16 Bs[BN * KCH];
    __shared__ int sSlot[BM], sPrev[BM], sAux[BM];
    int ntS = capS / BM;
    int bx = blockIdx.x;
    const int2* lst;
    int n, base;
    if (bx < ntS) {
        n = levelCount[2]; if (n > capS) n = capS;
        base = bx * BM;
        lst = levelList + offS;
    } else {
        n = levelCount[0]; if (n > CAP0) n = CAP0;
        base = (bx - ntS) * BM;
        lst = levelList;
    }
    if (base >= n) return;
    gemm_tile<0>(lst + base, min(BM, n - base), blockIdx.y,
                 xb, wihb, whhb, bih, bhh, slotOf, hb, cbuf, out, K,
                 As, Bs, sSlot, sPrev, sAux);
}

// ---------------------------------------------------------------- launch
extern "C" void kernel_launch(void* const* d_in, const int* in_sizes, int n_in,
                              void* d_out, int out_size, void* d_ws, size_t ws_size,
                              hipStream_t stream) {
    const float* x    = (const float*)d_in[0];
    const int* mask   = (const int*)d_in[1];
    const int* length = (const int*)d_in[2];
    const float* Wih  = (const float*)d_in[3];
    const float* Whh  = (const float*)d_in[4];
    const float* bih  = (const float*)d_in[5];
    const float* bhh  = (const float*)d_in[6];
    float* out = (float*)d_out;

    int K = (out_size - BB) / (BB * HH);
    int R = K + 64;
    int SLOTS = BB * R;
    int CAP0 = SLOTS;

    char* basep = (char*)d_ws;
    size_t off = 0;
    auto take = [&](size_t bytes) -> char* {
        off = (off + 255) & ~(size_t)255;
        char* p = basep + off;
        off += bytes;
        return p;
    };
    int* slotOf      = (int*)take((size_t)BT * 4);
    int* levelCount  = (int*)take(NBUCK * 4);
    int2* levelList  = (int2*)take((size_t)(CAP0 + LIST_EXTRA) * 8);
    u16* xb          = (u16*)take((size_t)SLOTS * II * 2);
    u16* hb          = (u16*)take((size_t)SLOTS * HH * 2);
    float* cbuf      = (float*)take((size_t)SLOTS * HH * 4);
    u16* wihb        = (u16*)take((size_t)GG * II * 2);
    u16* whhb        = (u16*)take((size_t)GG * HH * 2);
    (void)ws_size; (void)in_sizes; (void)n_in;

    k_wcvt<<<(GG * (II + HH) / 4 + 255) / 256, 256, 0, stream>>>(Wih, Whh, wihb, whhb, levelCount);
    k_prep<<<BB, 256, 0, stream>>>(mask, length, x, out + (size_t)BB * K * HH,
                                   levelCount, levelList, slotOf, xb, out, K, R, CAP0);

    int off_, cap_;
    // spine level 0 + leaves level 0 (both K=128, no W_hh), merged launch
    buck_geom(2, CAP0, &off_, &cap_);
    {
        int ntS = cap_ / BM;
        int nt0 = (CAP0 + BM - 1) / BM;
        k_big0<<<dim3(ntS + nt0, GG / BN), 256, 0, stream>>>(
            off_, cap_, CAP0, levelCount, levelList, xb, wihb, whhb, bih, bhh,
            slotOf, hb, cbuf, out, K);
    }
    // spine level 1 (K=640)
    buck_geom(3, CAP0, &off_, &cap_);
    k_gemm<1><<<dim3(cap_ / BM, GG / BN), 256, 0, stream>>>(
        3, off_, cap_, levelCount, levelList, xb, wihb, whhb, bih, bhh,
        slotOf, hb, cbuf, out, K);
    // spine levels 2..9: tiny launches, early-exit when empty
    for (int lev = 2; lev <= 9; ++lev) {
        buck_geom(2 + lev, CAP0, &off_, &cap_);
        k_gemm<1><<<dim3(1, GG / BN), 256, 0, stream>>>(
            2 + lev, off_, cap_, levelCount, levelList, xb, wihb, whhb, bih, bhh,
            slotOf, hb, cbuf, out, K);
    }
    // leaves with h (levels >=1), after full spine
    buck_geom(1, CAP0, &off_, &cap_);
    k_gemm<1><<<dim3(cap_ / BM, GG / BN), 256, 0, stream>>>(
        1, off_, cap_, levelCount, levelList, xb, wihb, whhb, bih, bhh,
        slotOf, hb, cbuf, out, K);
}

// Round 9
// 95.248 us; speedup vs baseline: 2.3363x; 1.0269x over previous
//
#include <hip/hip_runtime.h>
#include <math.h>

#define BB 128
#define TT 1024
#define II 128
#define HH 512
#define GG 2048           // 4*H
#define BT (BB*TT)
#define LMAX 10
#define NBUCK 20          // 0..9: leaf lvl0..9, 10..19: spine lvl0..9

#define BM 128            // rows per tile
#define BN 128            // gate cols per tile = 32 h-cols x 4 gates
#define KCH 128           // K chunk

typedef unsigned short u16;
typedef __attribute__((ext_vector_type(4))) u16 u16x4;
typedef __attribute__((ext_vector_type(8))) u16 u16x8;
typedef __attribute__((ext_vector_type(8))) short bf16x8;
typedef __attribute__((ext_vector_type(4))) float f32x4;

typedef __attribute__((address_space(3))) unsigned int lds_u32;
typedef __attribute__((address_space(1))) const unsigned int gbl_u32;

__device__ __forceinline__ void gload16(const void* g, void* l) {
    __builtin_amdgcn_global_load_lds((gbl_u32*)g, (lds_u32*)l, 16, 0, 0);
}

__device__ __forceinline__ float rcpf(float x) { return __builtin_amdgcn_rcpf(x); }
__device__ __forceinline__ float sigf(float v) { return rcpf(1.0f + __expf(-v)); }
__device__ __forceinline__ float tanhfast(float x) {
    float e = __expf(2.0f * x);
    return 1.0f - 2.0f * rcpf(e + 1.0f);
}

__device__ __forceinline__ u16 f2b(float f) {
    unsigned int x = __float_as_uint(f);
    return (u16)((x + 0x7fffu + ((x >> 16) & 1u)) >> 16);   // RNE, finite inputs
}

// bucket caps: leaf 0..9 then spine 0..9
__host__ __device__ __forceinline__ int buck_cap(int bkt, int CAP0) {
    if (bkt == 0) return CAP0;       // leaf lvl0 (the big one)
    if (bkt == 1) return 2048;       // leaf lvl1
    if (bkt == 2) return 256;        // leaf lvl2
    if (bkt == 3) return 128;        // leaf lvl3
    if (bkt <= 9) return 64;         // leaf lvl4..9
    if (bkt == 10) return 2048;      // spine lvl0
    if (bkt == 11) return 512;       // spine lvl1
    if (bkt == 12) return 128;       // spine lvl2
    return 64;                       // spine lvl3..9
}
__host__ __device__ __forceinline__ int buck_off(int bkt, int CAP0) {
    int o = 0;
    for (int i = 0; i < bkt; ++i) o += buck_cap(i, CAP0);
    return o;
}
#define LIST_EXTRA (2048 + 256 + 128 + 6*64 + 2048 + 512 + 128 + 7*64)

// wave-shuffle block scan (2 syncs)
__device__ __forceinline__ int block_scan_excl(int* ws4, int tid, int v, int* total) {
    int lane = tid & 63, wv = tid >> 6;
    int incl = v;
#pragma unroll
    for (int s = 1; s < 64; s <<= 1) {
        int u = __shfl_up(incl, (unsigned)s, 64);
        if (lane >= s) incl += u;
    }
    __syncthreads();
    if (lane == 63) ws4[wv] = incl;
    __syncthreads();
    int base = 0, tot = 0;
#pragma unroll
    for (int i = 0; i < 4; ++i) { int t = ws4[i]; if (i < wv) base += t; tot += t; }
    *total = tot;
    return base + incl - v;
}

// ---------------------------------------------------------------- k_prep (+wcvt blocks)
__global__ __launch_bounds__(256) void k_prep(
    const int* __restrict__ mask, const int* __restrict__ length,
    const float* __restrict__ x, float* __restrict__ wnOut,
    int* __restrict__ levelCount, int2* __restrict__ levelList,
    int* __restrict__ slotOf, u16* __restrict__ xb, float* __restrict__ out,
    const float* __restrict__ Wih, const float* __restrict__ Whh,
    u16* __restrict__ wihb, u16* __restrict__ whhb,
    int K, int R, int CAP0) {
    int tid = threadIdx.x;
    // ---- weight-convert blocks (independent of prep rows)
    if (blockIdx.x >= BB) {
        int i = (blockIdx.x - BB) * 256 + tid;
        const int NW = GG * II / 4;
        const int NH = GG * HH / 4;
        if (i < NW) {
            float4 v = ((const float4*)Wih)[i];
            u16x4 u = { f2b(v.x), f2b(v.y), f2b(v.z), f2b(v.w) };
            ((u16x4*)wihb)[i] = u;
        } else if (i < NW + NH) {
            int j = i - NW;
            float4 v = ((const float4*)Whh)[j];
            u16x4 u = { f2b(v.x), f2b(v.y), f2b(v.z), f2b(v.w) };
            ((u16x4*)whhb)[j] = u;
        }
        return;
    }

    __shared__ unsigned char sm[TT];
    __shared__ unsigned char sne[TT];
    __shared__ u16 sgp[TT];
    __shared__ int ws4[4];
    __shared__ int cnt[NBUCK], cnt2[NBUCK], bas[NBUCK], boff[NBUCK];
    __shared__ u16 spos[256];
    __shared__ u16 zlist[256];
    __shared__ int zn;

    int b = blockIdx.x;
    int len = length[b];
    int t0 = tid * 4;
    if (tid == 0) zn = 0;
    if (tid < NBUCK) { cnt[tid] = 0; cnt2[tid] = 0; boff[tid] = buck_off(tid, CAP0); }

    int4 mk = ((const int4*)(mask + (size_t)b * TT))[tid];
    int mraw[4] = { mk.x, mk.y, mk.z, mk.w };
    unsigned char mv[4];
    int lzero = 0;
#pragma unroll
    for (int j = 0; j < 4; ++j) {
        int t = t0 + j;
        unsigned char m = (t == len - 1) ? 1 : ((t == 0) ? 0 : (mraw[j] != 0));
        mv[j] = m;
        sm[t] = m;
        sgp[t] = 0;
        lzero += !m;
    }

    int Z;
    int zbase = block_scan_excl(ws4, tid, lzero, &Z);
    int wn = TT - Z;
    if (tid == 0) wnOut[b] = (float)wn;
    int need = K - wn;

    int psel[4];
    int lpad = 0;
    {
        int zb = zbase;
#pragma unroll
        for (int j = 0; j < 4; ++j) {
            int sel = mv[j] | ((Z - zb) <= need ? 1 : 0);
            psel[j] = sel;
            lpad += sel;
            zb += !mv[j];
        }
    }
    int ptot;
    int pbase = block_scan_excl(ws4, tid, lpad, &ptot);
    {
        int k = pbase;
#pragma unroll
        for (int j = 0; j < 4; ++j) {
            int t = t0 + j;
            if (psel[j]) {
                sgp[t - 1] = (u16)(k + 1);          // t==0 never selected (K << T)
                if (t - 1 >= len) {                 // inactive source -> zero out row
                    int zi = atomicAdd(&zn, 1);
                    if (zi < 256) zlist[zi] = (u16)k;
                }
                ++k;
            }
        }
    }
    __syncthreads();

    // needed (short forward chain walk) + chain level
    int nev[4], lvlv[4];
    int lne = 0;
#pragma unroll
    for (int j = 0; j < 4; ++j) {
        int t = t0 + j;
        int ne = 0;
        if (t < len) {
            int tt = t;
            ne = sgp[tt] != 0;
            while (!ne && tt + 1 < TT && tt + 1 < len && sm[tt + 1]) { ++tt; ne = sgp[tt] != 0; }
        }
        nev[j] = ne;
        sne[t] = (unsigned char)ne;
        lne += ne;
        int l = 0;
        if (mv[j]) { int tt = t; while (tt >= 0 && sm[tt] && l < LMAX - 1) { ++l; --tt; } }
        lvlv[j] = l;
    }

    int ntot;
    int nbase = block_scan_excl(ws4, tid, lne, &ntot);   // syncs inside; sne visible
    {
        int r = nbase;
        int sv[4];
#pragma unroll
        for (int j = 0; j < 4; ++j) {
            if (nev[j]) { sv[j] = b * R + r; if (r < 256) spos[r] = (u16)(t0 + j); }
            else sv[j] = -1;
            r += nev[j];
        }
        *(int4*)(slotOf + (size_t)b * TT + t0) = make_int4(sv[0], sv[1], sv[2], sv[3]);
    }
    __syncthreads();

    int bktv[4];
#pragma unroll
    for (int j = 0; j < 4; ++j) {
        bktv[j] = -1;
        if (nev[j]) {
            int t = t0 + j;
            int pred = (t + 1 < TT) && sm[t + 1] && sne[t + 1];
            int bkt = pred ? (10 + lvlv[j]) : lvlv[j];
            bktv[j] = bkt;
            atomicAdd(&cnt[bkt], 1);
        }
    }
    __syncthreads();
    if (tid < NBUCK) bas[tid] = cnt[tid] ? atomicAdd(&levelCount[tid], cnt[tid]) : 0;
    __syncthreads();
#pragma unroll
    for (int j = 0; j < 4; ++j) if (nev[j]) {
        int t = t0 + j;
        int bkt = bktv[j];
        int r = atomicAdd(&cnt2[bkt], 1);
        int idx = bas[bkt] + r;
        unsigned int y = ((bkt >= 10) ? 0x80000000u : 0u) | (unsigned int)sgp[t];
        if (idx < buck_cap(bkt, CAP0)) levelList[boff[bkt] + idx] = make_int2(b * TT + t, (int)y);
    }
    __syncthreads();

    // x rows of needed slots -> bf16
    int nv = (ntot < 256 ? ntot : 256) * 16;
    for (int idx = tid; idx < nv; idx += 256) {
        int r = idx >> 4, part = idx & 15;
        int t = spos[r];
        const float* src = x + ((size_t)b * TT + t) * II + part * 8;
        float4 v0 = ((const float4*)src)[0];
        float4 v1 = ((const float4*)src)[1];
        u16x8 u = { f2b(v0.x), f2b(v0.y), f2b(v0.z), f2b(v0.w),
                    f2b(v1.x), f2b(v1.y), f2b(v1.z), f2b(v1.w) };
        *(u16x8*)(xb + ((size_t)b * R + r) * II + part * 8) = u;
    }
    // zero gather rows with inactive sources
    int znv = zn < 256 ? zn : 256;
    for (int idx = tid; idx < znv * 128; idx += 256) {
        int e = idx >> 7, q = idx & 127;
        ((float4*)(out + ((size_t)b * K + zlist[e]) * HH))[q] = make_float4(0.f, 0.f, 0.f, 0.f);
    }
}

// ---------------------------------------------------------------- gemm tile (device)
// LDS linear dest via global_load_lds; per-lane global source pre-inverse-swizzled so
// LDS (row, byte c) holds source byte (c ^ ((row&7)<<4)); ds_reads swizzle identically.
template<int HASH>
__device__ __forceinline__ void gemm_tile(
    const int2* __restrict__ list, int nrow, int jg,
    const u16* __restrict__ xb, const u16* __restrict__ wihb, const u16* __restrict__ whhb,
    const float* __restrict__ bih, const float* __restrict__ bhh,
    const int* __restrict__ slotOf, u16* __restrict__ hb, float* __restrict__ cbuf,
    float* __restrict__ out, int K,
    u16* As, u16* Bs, int* sSlot, int* sPrev, int* sAux) {
    int tid = threadIdx.x;
    if (tid < BM) {
        int2 e = list[(tid < nrow) ? tid : 0];
        int pos = e.x;
        sSlot[tid] = slotOf[pos];
        sPrev[tid] = HASH ? slotOf[pos - 1] : 0;
        unsigned int y = (unsigned int)e.y;
        int grank = (int)(y & 0xFFFFu);
        sAux[tid] = (int)((y & 0x80000000u) | (unsigned int)(grank ? ((pos >> 10) * K + grank) : 0));
    }
    __syncthreads();

    int w = tid >> 6, l = tid & 63;
    int lrow = l >> 4;                 // row within a 1KB (4-row) DMA span
    int cbyte = (l & 15) << 4;         // 16B chunk within the 256B row
    f32x4 acc[2][8];
#pragma unroll
    for (int rb = 0; rb < 2; ++rb)
#pragma unroll
        for (int cb = 0; cb < 8; ++cb) acc[rb][cb] = (f32x4)0.f;

    const int nch = HASH ? 5 : 1;      // K chunks of 128
    for (int kc = 0; kc < nch; ++kc) {
        bool fromX = (kc == 0);
        int koff = kc * KCH - II;
#pragma unroll
        for (int i = 0; i < 8; ++i) {
            int rr = (w << 5) + (i << 2) + lrow;
            int so = cbyte ^ ((rr & 7) << 4);
            const char* srcA = fromX
                ? (const char*)(xb + (size_t)sSlot[rr] * II) + so
                : (const char*)(hb + (size_t)sPrev[rr] * HH + koff) + so;
            gload16(srcA, (char*)As + (w << 13) + (i << 10));
            int gj = (rr >> 5) * HH + jg * 32 + (rr & 31);
            const char* srcB = fromX
                ? (const char*)(wihb + (size_t)gj * II) + so
                : (const char*)(whhb + (size_t)gj * HH + koff) + so;
            gload16(srcB, (char*)Bs + (w << 13) + (i << 10));
        }
        __syncthreads();               // compiler drains vmcnt(0) before s_barrier
#pragma unroll
        for (int s = 0; s < 4; ++s) {
            bf16x8 af[2], bfr[8];
#pragma unroll
            for (int rb = 0; rb < 2; ++rb) {
                int rr = w * 32 + rb * 16 + (l & 15);
                int byte = rr * 256 + ((s * 64 + (l >> 4) * 16) ^ ((rr & 7) << 4));
                af[rb] = *(const bf16x8*)((const char*)As + byte);
            }
#pragma unroll
            for (int cb = 0; cb < 8; ++cb) {
                int rr = cb * 16 + (l & 15);
                int byte = rr * 256 + ((s * 64 + (l >> 4) * 16) ^ ((rr & 7) << 4));
                bfr[cb] = *(const bf16x8*)((const char*)Bs + byte);
            }
#pragma unroll
            for (int rb = 0; rb < 2; ++rb)
#pragma unroll
                for (int cb = 0; cb < 8; ++cb)
                    acc[rb][cb] = __builtin_amdgcn_mfma_f32_16x16x32_bf16(
                        af[rb], bfr[cb], acc[rb][cb], 0, 0, 0);
        }
        if (kc + 1 < nch) __syncthreads();
    }

    // epilogue: lane covers 2 h-cols (h0, h0+16) x 4 gates
    int u = l & 15;
    int h0 = jg * 32 + u;
    float b_i[2], b_f[2], b_g[2], b_o[2];
#pragma unroll
    for (int h = 0; h < 2; ++h) {
        int hc = h0 + h * 16;
        b_i[h] = bih[hc] + bhh[hc];
        b_f[h] = bih[HH + hc] + bhh[HH + hc];
        b_g[h] = bih[2 * HH + hc] + bhh[2 * HH + hc];
        b_o[h] = bih[3 * HH + hc] + bhh[3 * HH + hc];
    }
#pragma unroll
    for (int rb = 0; rb < 2; ++rb) {
#pragma unroll
        for (int r = 0; r < 4; ++r) {
            int m = w * 32 + rb * 16 + (l >> 4) * 4 + r;
            if (m < nrow) {
                int aux = sAux[m];
                int oi = aux & 0x7FFFFFFF;
                int sp = HASH ? sPrev[m] : 0;
                int sl = sSlot[m];
#pragma unroll
                for (int h = 0; h < 2; ++h) {
                    int hc = h0 + h * 16;
                    float gi = acc[rb][0 + h][r] + b_i[h];
                    float gf = acc[rb][2 + h][r] + b_f[h];
                    float gg = acc[rb][4 + h][r] + b_g[h];
                    float go = acc[rb][6 + h][r] + b_o[h];
                    float cin = HASH ? cbuf[(size_t)sp * HH + hc] : 0.f;
                    float c2 = sigf(gf) * cin + sigf(gi) * tanhfast(gg);
                    float h2 = sigf(go) * tanhfast(c2);
                    if (oi) out[(size_t)(oi - 1) * HH + hc] = h2;
                    if (aux < 0) {                      // spine: feed next level
                        hb[(size_t)sl * HH + hc] = f2b(h2);
                        cbuf[(size_t)sl * HH + hc] = c2;
                    }
                }
            }
        }
    }
}

// ---------------------------------------------------------------- k_dual (bucket A tiles, then bucket B tiles)
template<int HASH>
__global__ __launch_bounds__(256) void k_dual(
    int bktA, int offA, int capA, int bktB, int offB, int capB,
    const int* __restrict__ levelCount, const int2* __restrict__ levelList,
    const u16* __restrict__ xb, const u16* __restrict__ wihb, const u16* __restrict__ whhb,
    const float* __restrict__ bih, const float* __restrict__ bhh,
    const int* __restrict__ slotOf, u16* __restrict__ hb, float* __restrict__ cbuf,
    float* __restrict__ out, int K) {
    __shared__ __align__(16) u16 As[BM * KCH];
    __shared__ __align__(16) u16 Bs[BN * KCH];
    __shared__ int sSlot[BM], sPrev[BM], sAux[BM];
    int ntA = (capA + BM - 1) / BM;
    int bx = blockIdx.x;
    const int2* lst;
    int n, base;
    if (bx < ntA) {
        n = levelCount[bktA]; if (n > capA) n = capA;
        base = bx * BM;
        lst = levelList + offA;
    } else {
        n = levelCount[bktB]; if (n > capB) n = capB;
        base = (bx - ntA) * BM;
        lst = levelList + offB;
    }
    if (base >= n) return;
    gemm_tile<HASH>(lst + base, min(BM, n - base), blockIdx.y,
                    xb, wihb, whhb, bih, bhh, slotOf, hb, cbuf, out, K,
                    As, Bs, sSlot, sPrev, sAux);
}

// ---------------------------------------------------------------- k_tail59 (levels 5..9)
// grid (2,16); bx=0 -> spine tile, bx=1 -> leaf tile. Early-exits with no barrier
// when deeper levels are empty (the common case).
__global__ __launch_bounds__(256) void k_tail59(
    int CAP0, const int* __restrict__ levelCount, const int2* __restrict__ levelList,
    const u16* __restrict__ xb, const u16* __restrict__ wihb, const u16* __restrict__ whhb,
    const float* __restrict__ bih, const float* __restrict__ bhh,
    const int* __restrict__ slotOf, u16* __restrict__ hb, float* __restrict__ cbuf,
    float* __restrict__ out, int K, int* __restrict__ bar) {
    __shared__ __align__(16) u16 As[BM * KCH];
    __shared__ __align__(16) u16 Bs[BN * KCH];
    __shared__ int sSlot[BM], sPrev[BM], sAux[BM];
    int tid = threadIdx.x;
    int iter = 0;
    for (int l = 5; l <= 9; ++l) {
        int bkt = (blockIdx.x == 0) ? (10 + l) : l;
        int cap = buck_cap(bkt, CAP0);
        int n = levelCount[bkt]; if (n > cap) n = cap;
        if (n > 0) {
            gemm_tile<1>(levelList + buck_off(bkt, CAP0), min(BM, n), blockIdx.y,
                         xb, wihb, whhb, bih, bhh, slotOf, hb, cbuf, out, K,
                         As, Bs, sSlot, sPrev, sAux);
        }
        // any work at deeper levels?
        int rem = 0;
        for (int j = l + 1; j <= 9; ++j) {
            int a = levelCount[10 + j]; if (a > buck_cap(10 + j, CAP0)) a = buck_cap(10 + j, CAP0);
            int c = levelCount[j];      if (c > buck_cap(j, CAP0))      c = buck_cap(j, CAP0);
            rem += a + c;
        }
        ++iter;
        if (rem == 0) return;
        __threadfence();
        __syncthreads();
        if (tid == 0) {
            __hip_atomic_fetch_add(bar, 1, __ATOMIC_RELEASE, __HIP_MEMORY_SCOPE_AGENT);
            int target = 32 * iter;
            while (__hip_atomic_load(bar, __ATOMIC_ACQUIRE, __HIP_MEMORY_SCOPE_AGENT) < target) {
                __builtin_amdgcn_s_sleep(1);
            }
        }
        __syncthreads();
        __threadfence();
    }
}

// ---------------------------------------------------------------- launch
extern "C" void kernel_launch(void* const* d_in, const int* in_sizes, int n_in,
                              void* d_out, int out_size, void* d_ws, size_t ws_size,
                              hipStream_t stream) {
    const float* x    = (const float*)d_in[0];
    const int* mask   = (const int*)d_in[1];
    const int* length = (const int*)d_in[2];
    const float* Wih  = (const float*)d_in[3];
    const float* Whh  = (const float*)d_in[4];
    const float* bih  = (const float*)d_in[5];
    const float* bhh  = (const float*)d_in[6];
    float* out = (float*)d_out;

    int K = (out_size - BB) / (BB * HH);
    int R = K + 64;
    int SLOTS = BB * R;
    int CAP0 = SLOTS;

    char* basep = (char*)d_ws;
    size_t off = 0;
    auto take = [&](size_t bytes) -> char* {
        off = (off + 255) & ~(size_t)255;
        char* p = basep + off;
        off += bytes;
        return p;
    };
    int* slotOf      = (int*)take((size_t)BT * 4);
    int* levelCount  = (int*)take((NBUCK + 1) * 4);
    int2* levelList  = (int2*)take((size_t)(CAP0 + LIST_EXTRA) * 8);
    u16* xb          = (u16*)take((size_t)SLOTS * II * 2);
    u16* hb          = (u16*)take((size_t)SLOTS * HH * 2);
    float* cbuf      = (float*)take((size_t)SLOTS * HH * 4);
    u16* wihb        = (u16*)take((size_t)GG * II * 2);
    u16* whhb        = (u16*)take((size_t)GG * HH * 2);
    int* bar         = levelCount + NBUCK;
    (void)ws_size; (void)in_sizes; (void)n_in;

    hipMemsetAsync(levelCount, 0, (NBUCK + 1) * 4, stream);

    const int NWCVT = (GG * (II + HH) / 4 + 255) / 256;
    k_prep<<<BB + NWCVT, 256, 0, stream>>>(
        mask, length, x, out + (size_t)BB * K * HH,
        levelCount, levelList, slotOf, xb, out, Wih, Whh, wihb, whhb, K, R, CAP0);

    // level 0: spine0 + leaf0 (both K=128, no W_hh)
    {
        int oS = buck_off(10, CAP0), cS = buck_cap(10, CAP0);
        int ntS = (cS + BM - 1) / BM, ntL = (CAP0 + BM - 1) / BM;
        k_dual<0><<<dim3(ntS + ntL, GG / BN), 256, 0, stream>>>(
            10, oS, cS, 0, 0, CAP0, levelCount, levelList,
            xb, wihb, whhb, bih, bhh, slotOf, hb, cbuf, out, K);
    }
    // levels 1..4: spine_l + leaf_l (both depend only on spine_(l-1))
    for (int l = 1; l <= 4; ++l) {
        int oS = buck_off(10 + l, CAP0), cS = buck_cap(10 + l, CAP0);
        int oL = buck_off(l, CAP0),      cL = buck_cap(l, CAP0);
        int ntS = (cS + BM - 1) / BM, ntL = (cL + BM - 1) / BM;
        k_dual<1><<<dim3(ntS + ntL, GG / BN), 256, 0, stream>>>(
            10 + l, oS, cS, l, oL, cL, levelCount, levelList,
            xb, wihb, whhb, bih, bhh, slotOf, hb, cbuf, out, K);
    }
    // levels 5..9: one conditional-barrier kernel (usually early-exits)
    k_tail59<<<dim3(2, GG / BN), 256, 0, stream>>>(
        CAP0, levelCount, levelList, xb, wihb, whhb, bih, bhh,
        slotOf, hb, cbuf, out, K, bar);
}

// Round 11
// 89.493 us; speedup vs baseline: 2.4865x; 1.0643x over previous
//
#include <hip/hip_runtime.h>
#include <math.h>

#define BB 128
#define TT 1024
#define II 128
#define HH 512
#define GG 2048           // 4*H
#define BT (BB*TT)
#define LMAX 10
#define NBUCK 20          // 0..9: leaf lvl0..9, 10..19: spine lvl0..9

#define BM 128            // rows per tile
#define BN 128            // gate cols per tile = 32 h-cols x 4 gates
#define KCH 128           // K chunk

typedef unsigned short u16;
typedef __attribute__((ext_vector_type(4))) u16 u16x4;
typedef __attribute__((ext_vector_type(8))) u16 u16x8;
typedef __attribute__((ext_vector_type(8))) short bf16x8;
typedef __attribute__((ext_vector_type(4))) float f32x4;

typedef __attribute__((address_space(3))) unsigned int lds_u32;
typedef __attribute__((address_space(1))) const unsigned int gbl_u32;

__device__ __forceinline__ void gload16(const void* g, void* l) {
    __builtin_amdgcn_global_load_lds((gbl_u32*)g, (lds_u32*)l, 16, 0, 0);
}

__device__ __forceinline__ float rcpf(float x) { return __builtin_amdgcn_rcpf(x); }
__device__ __forceinline__ float sigf(float v) { return rcpf(1.0f + __expf(-v)); }
__device__ __forceinline__ float tanhfast(float x) {
    float e = __expf(2.0f * x);
    return 1.0f - 2.0f * rcpf(e + 1.0f);
}

__device__ __forceinline__ u16 f2b(float f) {
    unsigned int x = __float_as_uint(f);
    return (u16)((x + 0x7fffu + ((x >> 16) & 1u)) >> 16);   // RNE, finite inputs
}

// bucket caps: leaf 0..9 then spine 0..9
__host__ __device__ __forceinline__ int buck_cap(int bkt, int CAP0) {
    if (bkt == 0) return CAP0;       // leaf lvl0 (the big one)
    if (bkt == 1) return 2048;       // leaf lvl1
    if (bkt == 2) return 256;        // leaf lvl2
    if (bkt <= 9) return 128;        // leaf lvl3..9 (single tile)
    if (bkt == 10) return 2048;      // spine lvl0
    if (bkt == 11) return 512;       // spine lvl1
    if (bkt == 12) return 128;       // spine lvl2
    return 64;                       // spine lvl3..9
}
__host__ __device__ __forceinline__ int buck_off(int bkt, int CAP0) {
    int o = 0;
    for (int i = 0; i < bkt; ++i) o += buck_cap(i, CAP0);
    return o;
}
#define LIST_EXTRA (2048 + 256 + 7*128 + 2048 + 512 + 128 + 7*64)

// wave-shuffle block scan (2 syncs)
__device__ __forceinline__ int block_scan_excl(int* ws4, int tid, int v, int* total) {
    int lane = tid & 63, wv = tid >> 6;
    int incl = v;
#pragma unroll
    for (int s = 1; s < 64; s <<= 1) {
        int u = __shfl_up(incl, (unsigned)s, 64);
        if (lane >= s) incl += u;
    }
    __syncthreads();
    if (lane == 63) ws4[wv] = incl;
    __syncthreads();
    int base = 0, tot = 0;
#pragma unroll
    for (int i = 0; i < 4; ++i) { int t = ws4[i]; if (i < wv) base += t; tot += t; }
    *total = tot;
    return base + incl - v;
}

// ---------------------------------------------------------------- k_prep (+wcvt blocks)
__global__ __launch_bounds__(256) void k_prep(
    const int* __restrict__ mask, const int* __restrict__ length,
    const float* __restrict__ x, float* __restrict__ wnOut,
    int* __restrict__ levelCount, int2* __restrict__ levelList,
    int* __restrict__ slotOf, u16* __restrict__ xb, float* __restrict__ out,
    const float* __restrict__ Wih, const float* __restrict__ Whh,
    u16* __restrict__ wihb, u16* __restrict__ whhb,
    int K, int R, int CAP0) {
    int tid = threadIdx.x;
    // ---- weight-convert blocks (independent of prep rows)
    if (blockIdx.x >= BB) {
        int i = (blockIdx.x - BB) * 256 + tid;
        const int NW = GG * II / 4;
        const int NH = GG * HH / 4;
        if (i < NW) {
            float4 v = ((const float4*)Wih)[i];
            u16x4 u = { f2b(v.x), f2b(v.y), f2b(v.z), f2b(v.w) };
            ((u16x4*)wihb)[i] = u;
        } else if (i < NW + NH) {
            int j = i - NW;
            float4 v = ((const float4*)Whh)[j];
            u16x4 u = { f2b(v.x), f2b(v.y), f2b(v.z), f2b(v.w) };
            ((u16x4*)whhb)[j] = u;
        }
        return;
    }

    __shared__ unsigned char sm[TT];
    __shared__ unsigned char sne[TT];
    __shared__ u16 sgp[TT];
    __shared__ int ws4[4];
    __shared__ int cnt[NBUCK], cnt2[NBUCK], bas[NBUCK], boff[NBUCK];
    __shared__ u16 spos[256];
    __shared__ u16 zlist[256];
    __shared__ int zn;

    int b = blockIdx.x;
    int len = length[b];
    int t0 = tid * 4;
    if (tid == 0) zn = 0;
    if (tid < NBUCK) { cnt[tid] = 0; cnt2[tid] = 0; boff[tid] = buck_off(tid, CAP0); }

    int4 mk = ((const int4*)(mask + (size_t)b * TT))[tid];
    int mraw[4] = { mk.x, mk.y, mk.z, mk.w };
    unsigned char mv[4];
    int lzero = 0;
#pragma unroll
    for (int j = 0; j < 4; ++j) {
        int t = t0 + j;
        unsigned char m = (t == len - 1) ? 1 : ((t == 0) ? 0 : (mraw[j] != 0));
        mv[j] = m;
        sm[t] = m;
        sgp[t] = 0;
        lzero += !m;
    }

    int Z;
    int zbase = block_scan_excl(ws4, tid, lzero, &Z);
    int wn = TT - Z;
    if (tid == 0) wnOut[b] = (float)wn;
    int need = K - wn;

    int psel[4];
    int lpad = 0;
    {
        int zb = zbase;
#pragma unroll
        for (int j = 0; j < 4; ++j) {
            int sel = mv[j] | ((Z - zb) <= need ? 1 : 0);
            psel[j] = sel;
            lpad += sel;
            zb += !mv[j];
        }
    }
    int ptot;
    int pbase = block_scan_excl(ws4, tid, lpad, &ptot);
    {
        int k = pbase;
#pragma unroll
        for (int j = 0; j < 4; ++j) {
            int t = t0 + j;
            if (psel[j]) {
                sgp[t - 1] = (u16)(k + 1);          // t==0 never selected (K << T)
                if (t - 1 >= len) {                 // inactive source -> zero out row
                    int zi = atomicAdd(&zn, 1);
                    if (zi < 256) zlist[zi] = (u16)k;
                }
                ++k;
            }
        }
    }
    __syncthreads();

    // needed (short forward chain walk) + chain level
    int nev[4], lvlv[4];
    int lne = 0;
#pragma unroll
    for (int j = 0; j < 4; ++j) {
        int t = t0 + j;
        int ne = 0;
        if (t < len) {
            int tt = t;
            ne = sgp[tt] != 0;
            while (!ne && tt + 1 < TT && tt + 1 < len && sm[tt + 1]) { ++tt; ne = sgp[tt] != 0; }
        }
        nev[j] = ne;
        sne[t] = (unsigned char)ne;
        lne += ne;
        int l = 0;
        if (mv[j]) { int tt = t; while (tt >= 0 && sm[tt] && l < LMAX - 1) { ++l; --tt; } }
        lvlv[j] = l;
    }

    int ntot;
    int nbase = block_scan_excl(ws4, tid, lne, &ntot);   // syncs inside; sne visible
    {
        int r = nbase;
        int sv[4];
#pragma unroll
        for (int j = 0; j < 4; ++j) {
            if (nev[j]) { sv[j] = b * R + r; if (r < 256) spos[r] = (u16)(t0 + j); }
            else sv[j] = -1;
            r += nev[j];
        }
        *(int4*)(slotOf + (size_t)b * TT + t0) = make_int4(sv[0], sv[1], sv[2], sv[3]);
    }
    __syncthreads();

    int bktv[4];
#pragma unroll
    for (int j = 0; j < 4; ++j) {
        bktv[j] = -1;
        if (nev[j]) {
            int t = t0 + j;
            int pred = (t + 1 < TT) && sm[t + 1] && sne[t + 1];
            int bkt = pred ? (10 + lvlv[j]) : lvlv[j];
            bktv[j] = bkt;
            atomicAdd(&cnt[bkt], 1);
        }
    }
    __syncthreads();
    if (tid < NBUCK) bas[tid] = cnt[tid] ? atomicAdd(&levelCount[tid], cnt[tid]) : 0;
    __syncthreads();
#pragma unroll
    for (int j = 0; j < 4; ++j) if (nev[j]) {
        int t = t0 + j;
        int bkt = bktv[j];
        int r = atomicAdd(&cnt2[bkt], 1);
        int idx = bas[bkt] + r;
        unsigned int y = ((bkt >= 10) ? 0x80000000u : 0u) | (unsigned int)sgp[t];
        if (idx < buck_cap(bkt, CAP0)) levelList[boff[bkt] + idx] = make_int2(b * TT + t, (int)y);
    }
    __syncthreads();

    // x rows of needed slots -> bf16
    int nv = (ntot < 256 ? ntot : 256) * 16;
    for (int idx = tid; idx < nv; idx += 256) {
        int r = idx >> 4, part = idx & 15;
        int t = spos[r];
        const float* src = x + ((size_t)b * TT + t) * II + part * 8;
        float4 v0 = ((const float4*)src)[0];
        float4 v1 = ((const float4*)src)[1];
        u16x8 u = { f2b(v0.x), f2b(v0.y), f2b(v0.z), f2b(v0.w),
                    f2b(v1.x), f2b(v1.y), f2b(v1.z), f2b(v1.w) };
        *(u16x8*)(xb + ((size_t)b * R + r) * II + part * 8) = u;
    }
    // zero gather rows with inactive sources
    int znv = zn < 256 ? zn : 256;
    for (int idx = tid; idx < znv * 128; idx += 256) {
        int e = idx >> 7, q = idx & 127;
        ((float4*)(out + ((size_t)b * K + zlist[e]) * HH))[q] = make_float4(0.f, 0.f, 0.f, 0.f);
    }
}

// ---------------------------------------------------------------- gemm tile (device)
// LDS linear dest via global_load_lds; per-lane global source pre-inverse-swizzled so
// LDS (row, byte c) holds source byte (c ^ ((row&7)<<4)); ds_reads swizzle identically.
template<int HASH>
__device__ __forceinline__ void gemm_tile(
    const int2* __restrict__ list, int nrow, int jg,
    const u16* __restrict__ xb, const u16* __restrict__ wihb, const u16* __restrict__ whhb,
    const float* __restrict__ bih, const float* __restrict__ bhh,
    const int* __restrict__ slotOf, u16* __restrict__ hb, float* __restrict__ cbuf,
    float* __restrict__ out, int K,
    u16* As, u16* Bs, int* sSlot, int* sPrev, int* sAux) {
    int tid = threadIdx.x;
    if (tid < BM) {
        int2 e = list[(tid < nrow) ? tid : 0];
        int pos = e.x;
        sSlot[tid] = slotOf[pos];
        sPrev[tid] = HASH ? slotOf[pos - 1] : 0;
        unsigned int y = (unsigned int)e.y;
        int grank = (int)(y & 0xFFFFu);
        sAux[tid] = (int)((y & 0x80000000u) | (unsigned int)(grank ? ((pos >> 10) * K + grank) : 0));
    }
    __syncthreads();

    int w = tid >> 6, l = tid & 63;
    int lrow = l >> 4;                 // row within a 1KB (4-row) DMA span
    int cbyte = (l & 15) << 4;         // 16B chunk within the 256B row
    f32x4 acc[2][8];
#pragma unroll
    for (int rb = 0; rb < 2; ++rb)
#pragma unroll
        for (int cb = 0; cb < 8; ++cb) acc[rb][cb] = (f32x4)0.f;

    const int nch = HASH ? 5 : 1;      // K chunks of 128
    for (int kc = 0; kc < nch; ++kc) {
        bool fromX = (kc == 0);
        int koff = kc * KCH - II;
#pragma unroll
        for (int i = 0; i < 8; ++i) {
            int rr = (w << 5) + (i << 2) + lrow;
            int so = cbyte ^ ((rr & 7) << 4);
            const char* srcA = fromX
                ? (const char*)(xb + (size_t)sSlot[rr] * II) + so
                : (const char*)(hb + (size_t)sPrev[rr] * HH + koff) + so;
            gload16(srcA, (char*)As + (w << 13) + (i << 10));
            int gj = (rr >> 5) * HH + jg * 32 + (rr & 31);
            const char* srcB = fromX
                ? (const char*)(wihb + (size_t)gj * II) + so
                : (const char*)(whhb + (size_t)gj * HH + koff) + so;
            gload16(srcB, (char*)Bs + (w << 13) + (i << 10));
        }
        __syncthreads();               // compiler drains vmcnt(0) before s_barrier
#pragma unroll
        for (int s = 0; s < 4; ++s) {
            bf16x8 af[2], bfr[8];
#pragma unroll
            for (int rb = 0; rb < 2; ++rb) {
                int rr = w * 32 + rb * 16 + (l & 15);
                int byte = rr * 256 + ((s * 64 + (l >> 4) * 16) ^ ((rr & 7) << 4));
                af[rb] = *(const bf16x8*)((const char*)As + byte);
            }
#pragma unroll
            for (int cb = 0; cb < 8; ++cb) {
                int rr = cb * 16 + (l & 15);
                int byte = rr * 256 + ((s * 64 + (l >> 4) * 16) ^ ((rr & 7) << 4));
                bfr[cb] = *(const bf16x8*)((const char*)Bs + byte);
            }
#pragma unroll
            for (int rb = 0; rb < 2; ++rb)
#pragma unroll
                for (int cb = 0; cb < 8; ++cb)
                    acc[rb][cb] = __builtin_amdgcn_mfma_f32_16x16x32_bf16(
                        af[rb], bfr[cb], acc[rb][cb], 0, 0, 0);
        }
        if (kc + 1 < nch) __syncthreads();
    }

    // epilogue: lane covers 2 h-cols (h0, h0+16) x 4 gates
    int u = l & 15;
    int h0 = jg * 32 + u;
    float b_i[2], b_f[2], b_g[2], b_o[2];
#pragma unroll
    for (int h = 0; h < 2; ++h) {
        int hc = h0 + h * 16;
        b_i[h] = bih[hc] + bhh[hc];
        b_f[h] = bih[HH + hc] + bhh[HH + hc];
        b_g[h] = bih[2 * HH + hc] + bhh[2 * HH + hc];
        b_o[h] = bih[3 * HH + hc] + bhh[3 * HH + hc];
    }
#pragma unroll
    for (int rb = 0; rb < 2; ++rb) {
#pragma unroll
        for (int r = 0; r < 4; ++r) {
            int m = w * 32 + rb * 16 + (l >> 4) * 4 + r;
            if (m < nrow) {
                int aux = sAux[m];
                int oi = aux & 0x7FFFFFFF;
                int sp = HASH ? sPrev[m] : 0;
                int sl = sSlot[m];
#pragma unroll
                for (int h = 0; h < 2; ++h) {
                    int hc = h0 + h * 16;
                    float gi = acc[rb][0 + h][r] + b_i[h];
                    float gf = acc[rb][2 + h][r] + b_f[h];
                    float gg = acc[rb][4 + h][r] + b_g[h];
                    float go = acc[rb][6 + h][r] + b_o[h];
                    float cin = HASH ? cbuf[(size_t)sp * HH + hc] : 0.f;
                    float c2 = sigf(gf) * cin + sigf(gi) * tanhfast(gg);
                    float h2 = sigf(go) * tanhfast(c2);
                    if (oi) out[(size_t)(oi - 1) * HH + hc] = h2;
                    if (aux < 0) {                      // spine: feed next level
                        hb[(size_t)sl * HH + hc] = f2b(h2);
                        cbuf[(size_t)sl * HH + hc] = c2;
                    }
                }
            }
        }
    }
}

// ---------------------------------------------------------------- k_dual (1D grid, XCD-grouped)
// virtual tile v and jg decoded so that all 16 jg-blocks of a tile share bid&7
// (same XCD L2) -> A-slice fetched once per XCD instead of once per block wave.
template<int HASH>
__global__ __launch_bounds__(256) void k_dual(
    int bktA, int offA, int capA, int ntA,
    int bktB, int offB, int capB, int ntTot,
    const int* __restrict__ levelCount, const int2* __restrict__ levelList,
    const u16* __restrict__ xb, const u16* __restrict__ wihb, const u16* __restrict__ whhb,
    const float* __restrict__ bih, const float* __restrict__ bhh,
    const int* __restrict__ slotOf, u16* __restrict__ hb, float* __restrict__ cbuf,
    float* __restrict__ out, int K) {
    __shared__ __align__(16) u16 As[BM * KCH];
    __shared__ __align__(16) u16 Bs[BN * KCH];
    __shared__ int sSlot[BM], sPrev[BM], sAux[BM];
    int bid = (int)blockIdx.x;
    int xcd = bid & 7, q = bid >> 3;
    int jg = q & 15;
    int v = ((q >> 4) << 3) + xcd;
    if (v >= ntTot) return;
    const int2* lst;
    int n, base;
    if (v < ntA) {
        n = levelCount[bktA]; if (n > capA) n = capA;
        base = v * BM;
        lst = levelList + offA;
    } else {
        n = levelCount[bktB]; if (n > capB) n = capB;
        base = (v - ntA) * BM;
        lst = levelList + offB;
    }
    if (base >= n) return;
    gemm_tile<HASH>(lst + base, min(BM, n - base), jg,
                    xb, wihb, whhb, bih, bhh, slotOf, hb, cbuf, out, K,
                    As, Bs, sSlot, sPrev, sAux);
}

// ---------------------------------------------------------------- k_tail39 (levels 3..9)
// grid (2,16); bx=0 -> spine tile, bx=1 -> leaf tile. Early-exits with no barrier
// when deeper levels are empty (the common case). Round-8-proven pattern.
__global__ __launch_bounds__(256) void k_tail39(
    int CAP0, const int* __restrict__ levelCount, const int2* __restrict__ levelList,
    const u16* __restrict__ xb, const u16* __restrict__ wihb, const u16* __restrict__ whhb,
    const float* __restrict__ bih, const float* __restrict__ bhh,
    const int* __restrict__ slotOf, u16* __restrict__ hb, float* __restrict__ cbuf,
    float* __restrict__ out, int K, int* __restrict__ bar) {
    __shared__ __align__(16) u16 As[BM * KCH];
    __shared__ __align__(16) u16 Bs[BN * KCH];
    __shared__ int sSlot[BM], sPrev[BM], sAux[BM];
    int tid = threadIdx.x;
    int iter = 0;
    for (int l = 3; l <= 9; ++l) {
        int bkt = (blockIdx.x == 0) ? (10 + l) : l;
        int cap = buck_cap(bkt, CAP0);
        int n = levelCount[bkt]; if (n > cap) n = cap;
        if (n > 0) {
            gemm_tile<1>(levelList + buck_off(bkt, CAP0), min(BM, n), blockIdx.y,
                         xb, wihb, whhb, bih, bhh, slotOf, hb, cbuf, out, K,
                         As, Bs, sSlot, sPrev, sAux);
        }
        // any work at deeper levels?
        int rem = 0;
        for (int j = l + 1; j <= 9; ++j) {
            int a = levelCount[10 + j]; if (a > buck_cap(10 + j, CAP0)) a = buck_cap(10 + j, CAP0);
            int c = levelCount[j];      if (c > buck_cap(j, CAP0))      c = buck_cap(j, CAP0);
            rem += a + c;
        }
        ++iter;
        if (rem == 0) return;
        __threadfence();
        __syncthreads();
        if (tid == 0) {
            __hip_atomic_fetch_add(bar, 1, __ATOMIC_RELEASE, __HIP_MEMORY_SCOPE_AGENT);
            int target = 32 * iter;
            while (__hip_atomic_load(bar, __ATOMIC_ACQUIRE, __HIP_MEMORY_SCOPE_AGENT) < target) {
                __builtin_amdgcn_s_sleep(1);
            }
        }
        __syncthreads();
        __threadfence();
    }
}

// ---------------------------------------------------------------- launch
extern "C" void kernel_launch(void* const* d_in, const int* in_sizes, int n_in,
                              void* d_out, int out_size, void* d_ws, size_t ws_size,
                              hipStream_t stream) {
    const float* x    = (const float*)d_in[0];
    const int* mask   = (const int*)d_in[1];
    const int* length = (const int*)d_in[2];
    const float* Wih  = (const float*)d_in[3];
    const float* Whh  = (const float*)d_in[4];
    const float* bih  = (const float*)d_in[5];
    const float* bhh  = (const float*)d_in[6];
    float* out = (float*)d_out;

    int K = (out_size - BB) / (BB * HH);
    int R = K + 64;
    int SLOTS = BB * R;
    int CAP0 = SLOTS;

    char* basep = (char*)d_ws;
    size_t off = 0;
    auto take = [&](size_t bytes) -> char* {
        off = (off + 255) & ~(size_t)255;
        char* p = basep + off;
        off += bytes;
        return p;
    };
    int* slotOf      = (int*)take((size_t)BT * 4);
    int* levelCount  = (int*)take((NBUCK + 1) * 4);
    int2* levelList  = (int2*)take((size_t)(CAP0 + LIST_EXTRA) * 8);
    u16* xb          = (u16*)take((size_t)SLOTS * II * 2);
    u16* hb          = (u16*)take((size_t)SLOTS * HH * 2);
    float* cbuf      = (float*)take((size_t)SLOTS * HH * 4);
    u16* wihb        = (u16*)take((size_t)GG * II * 2);
    u16* whhb        = (u16*)take((size_t)GG * HH * 2);
    int* bar         = levelCount + NBUCK;
    (void)ws_size; (void)in_sizes; (void)n_in;

    hipMemsetAsync(levelCount, 0, (NBUCK + 1) * 4, stream);

    const int NWCVT = (GG * (II + HH) / 4 + 255) / 256;
    k_prep<<<BB + NWCVT, 256, 0, stream>>>(
        mask, length, x, out + (size_t)BB * K * HH,
        levelCount, levelList, slotOf, xb, out, Wih, Whh, wihb, whhb, K, R, CAP0);

    // level 0: spine0 + leaf0 (both K=128, no W_hh)
    {
        int oS = buck_off(10, CAP0), cS = buck_cap(10, CAP0);
        int ntS = (cS + BM - 1) / BM;
        int ntTot = ntS + (CAP0 + BM - 1) / BM;
        int nv8 = (ntTot + 7) & ~7;
        k_dual<0><<<dim3(nv8 * 16, 1), 256, 0, stream>>>(
            10, oS, cS, ntS, 0, 0, CAP0, ntTot, levelCount, levelList,
            xb, wihb, whhb, bih, bhh, slotOf, hb, cbuf, out, K);
    }
    // levels 1..2: spine_l + leaf_l (both depend only on spine_(l-1))
    for (int l = 1; l <= 2; ++l) {
        int oS = buck_off(10 + l, CAP0), cS = buck_cap(10 + l, CAP0);
        int oL = buck_off(l, CAP0),      cL = buck_cap(l, CAP0);
        int ntS = (cS + BM - 1) / BM;
        int ntTot = ntS + (cL + BM - 1) / BM;
        int nv8 = (ntTot + 7) & ~7;
        k_dual<1><<<dim3(nv8 * 16, 1), 256, 0, stream>>>(
            10 + l, oS, cS, ntS, l, oL, cL, ntTot, levelCount, levelList,
            xb, wihb, whhb, bih, bhh, slotOf, hb, cbuf, out, K);
    }
    // levels 3..9: one conditional-barrier kernel (usually 1-2 rounds)
    k_tail39<<<dim3(2, 16), 256, 0, stream>>>(
        CAP0, levelCount, levelList, xb, wihb, whhb, bih, bhh,
        slotOf, hb, cbuf, out, K, bar);
}